// Round 18
// baseline (659.433 us; speedup 1.0000x reference)
//
#include <hip/hip_runtime.h>
#include <cstddef>
#include <cstdint>

#define BN_EPS 1e-5f

typedef float f2 __attribute__((ext_vector_type(2)));
typedef float f4 __attribute__((ext_vector_type(4)));
typedef float f32x4 __attribute__((ext_vector_type(4)));
typedef _Float16 h2 __attribute__((ext_vector_type(2)));
typedef _Float16 h8 __attribute__((ext_vector_type(8)));

// ---------------------------------------------------------------------------
// Bijective XCD-chunked block swizzle. Kept ONLY in sconv0t (helps there:
// FETCH 92->31MB; regressed the MFMA convs when applied to them).
// ---------------------------------------------------------------------------
__device__ __forceinline__ int xcd_swz(int bid, int nwg)
{
    const int q = nwg >> 3, r = nwg & 7;
    const int xcd = bid & 7, idx = bid >> 3;
    const int base = (xcd < r) ? xcd * (q + 1) : r * (q + 1) + (xcd - r) * q;
    return base + idx;
}

// ---------------------------------------------------------------------------
// MFMA weight transform: W[27][CIN][COUT] fp32 -> B-fragment layout f16.
// ---------------------------------------------------------------------------
template<int CIN, int COUT>
__global__ __launch_bounds__(256)
void wtrans_mf(const float* __restrict__ W, _Float16* __restrict__ Wm)
{
    constexpr int NT = CIN / 32;
    constexpr int NC = COUT / 16;
    const int t = blockIdx.x * 256 + threadIdx.x;
    constexpr int TOTAL = 27 * NT * NC * 64;
    if (t >= TOTAL) return;
    const int lane = t & 63;
    int rest = t >> 6;
    const int ct = rest % NC; rest /= NC;
    const int tt = rest % NT;
    const int k  = rest / NT;
    const int cin0 = tt * 32 + (lane >> 4) * 8;
    const int co   = ct * 16 + (lane & 15);
    h8 v;
    #pragma unroll
    for (int u = 0; u < 8; ++u)
        v[u] = (_Float16)W[((size_t)k * CIN + cin0 + u) * COUT + co];
    *(h8*)(Wm + (size_t)t * 8) = v;
}

// ---------------------------------------------------------------------------
// conv0 MFMA weight transform (CIN=16, COUT=32, k-PAIRED).
// ---------------------------------------------------------------------------
__global__ __launch_bounds__(256)
void wtrans_mf0(const float* __restrict__ W, _Float16* __restrict__ Wm0)
{
    const int t = blockIdx.x * 256 + threadIdx.x;
    constexpr int TOTAL = 27 * 2 * 32;
    if (t >= TOTAL) return;
    const int co = t % 32;
    const int s  = (t / 32) % 2;
    const int k  = t / 64;
    h8 v;
    #pragma unroll
    for (int u = 0; u < 8; ++u)
        v[u] = (_Float16)W[((size_t)k * 16 + s * 8 + u) * 32 + co];
    *(h8*)(Wm0 + (size_t)t * 8) = v;
}

// ---------------------------------------------------------------------------
// Pass A: map transpose + parity-class byte + LDS-aggregated histogram.
// ---------------------------------------------------------------------------
__global__ __launch_bounds__(256)
void map_transpose_cls(const int* __restrict__ map, int Nout,
                       int* __restrict__ mapT, unsigned char* __restrict__ cls,
                       int* __restrict__ counts)
{
    __shared__ int s[256][28];
    __shared__ int hist[9];
    const int tid  = threadIdx.x;
    const int base = blockIdx.x * 256;
    const int j    = base + tid;
    if (tid < 9) hist[tid] = 0;
    for (int k = 0; k < 27; ++k)
        s[tid][k] = (j < Nout) ? map[(size_t)k * Nout + j] : -1;
    __syncthreads();
    for (int i = tid; i < 256 * 32; i += 256) {
        const int r = i >> 5, c = i & 31;
        if (base + r < Nout)
            mapT[(size_t)(base + r) * 32 + c] = (c < 27) ? s[r][c] : -1;
    }
    if (j < Nout) {
        int c9 = 8;
        #pragma unroll 1
        for (int k = 0; k < 27; ++k) {
            if (s[tid][k] >= 0) {
                const int dz = k % 3, dy = (k / 3) % 3, dx = k / 9;
                c9 = ((dx != 1) << 2) | ((dy != 1) << 1) | (int)(dz != 1);
                break;
            }
        }
        cls[j] = (unsigned char)c9;
        atomicAdd(&hist[c9], 1);
    }
    __syncthreads();
    if (tid < 9 && hist[tid] > 0)
        atomicAdd(&counts[tid], hist[tid]);
}

// ---------------------------------------------------------------------------
// Pass C: COMPACT class-grouped scatter (dense order[], no dead slots).
// ---------------------------------------------------------------------------
__global__ __launch_bounds__(256)
void scatter_compact(const unsigned char* __restrict__ cls, int Nout,
                     const int* __restrict__ counts, int* __restrict__ cursors,
                     int* __restrict__ order)
{
    __shared__ int hist[9], basec[9];
    const int tid = threadIdx.x;
    const int j   = blockIdx.x * 256 + tid;
    if (tid < 9) hist[tid] = 0;
    const int c9 = (j < Nout) ? (int)cls[j] : -1;
    __syncthreads();
    int lpos = 0;
    if (c9 >= 0) lpos = atomicAdd(&hist[c9], 1);
    __syncthreads();
    if (tid < 9 && hist[tid] > 0)
        basec[tid] = atomicAdd(&cursors[tid], hist[tid]);
    __syncthreads();
    if (c9 >= 0) {
        int offs = 0;
        #pragma unroll
        for (int c = 0; c < 9; ++c)
            if (c < c9) offs += counts[c];
        order[offs + basec[c9] + lpos] = j;
    }
}

// ---------------------------------------------------------------------------
// conv0 MFMA (CIN=16 fp32 in, COUT=32, k-PAIRED, compensated hi/lo).
// Round-18: BN pass-1 fused into the epilogue (partials of the STORED f16
// values; padded rows contribute exact zeros).
// ---------------------------------------------------------------------------
__global__ __launch_bounds__(256)
void sconv_mf0(const float* __restrict__ x, const _Float16* __restrict__ Wm0,
               const int* __restrict__ map, int Nout,
               _Float16* __restrict__ out, const float* __restrict__ zrow,
               float* __restrict__ sums)
{
    const int tid  = threadIdx.x;
    const int lane = tid & 63;
    const int wave = tid >> 6;
    const int row0 = (blockIdx.x * 4 + wave) * 16;

    __shared__ int smap[4][16][28];
    __shared__ float bsum[2][32];

    if (tid < 32) { bsum[0][tid] = 0.f; bsum[1][tid] = 0.f; }

    int mk[16];
    bool anyv = false;
    #pragma unroll
    for (int r = 0; r < 16; ++r) {
        const int j = row0 + r;
        mk[r] = (lane < 27 && j < Nout) ? map[(size_t)lane * Nout + j] : -1;
        anyv |= (mk[r] >= 0);
    }
    unsigned long long act = __ballot(anyv);

    if (lane < 27) {
        #pragma unroll
        for (int r = 0; r < 16; ++r)
            smap[wave][r][lane] = mk[r];
    }

    f32x4 accH[2], accL[2];
    #pragma unroll
    for (int c = 0; c < 2; ++c) {
        accH[c] = (f32x4){0.f, 0.f, 0.f, 0.f};
        accL[c] = (f32x4){0.f, 0.f, 0.f, 0.f};
    }

    const int rrow = lane & 15;   // A row / D col
    const int kseg = lane >> 4;
    const int half = kseg & 1;    // cin half: 0 -> 0..7, 1 -> 8..15
    const bool useK1 = (kseg < 2);

    while (act) {
        const int k1 = (int)__builtin_ctzll(act);
        act &= act - 1;
        int k2 = -1;
        if (act) {
            k2 = (int)__builtin_ctzll(act);
            act &= act - 1;
        }
        const int ks = useK1 ? k1 : k2;
        int m = -1;
        if (ks >= 0) m = smap[wave][rrow][ks];

        const float* px = (m >= 0) ? (x + (size_t)m * 16 + half * 8)
                                   : (zrow + half * 8);
        const f4 x0 = *(const f4*)px;
        const f4 x1 = *(const f4*)(px + 4);
        h8 aH, aL;
        #pragma unroll
        for (int u = 0; u < 4; ++u) {
            const float v0 = x0[u], v1 = x1[u];
            const _Float16 h0 = (_Float16)v0;
            const _Float16 h1 = (_Float16)v1;
            aH[u]     = h0;
            aH[u + 4] = h1;
            aL[u]     = (_Float16)((v0 - (float)h0) * 2048.f);
            aL[u + 4] = (_Float16)((v1 - (float)h1) * 2048.f);
        }

        const int ksafe = (ks >= 0) ? ks : 0;   // a==0 makes b irrelevant
        const _Float16* wb = Wm0 + ((size_t)(ksafe * 2 + half) * 32) * 8;
        #pragma unroll
        for (int c = 0; c < 2; ++c) {
            const h8 b = *(const h8*)(wb + (size_t)(c * 16 + rrow) * 8);
            accH[c] = __builtin_amdgcn_mfma_f32_16x16x32_f16(aH, b, accH[c], 0, 0, 0);
            accL[c] = __builtin_amdgcn_mfma_f32_16x16x32_f16(aL, b, accL[c], 0, 0, 0);
        }
    }

    float ps[2], pq[2];
    #pragma unroll
    for (int c = 0; c < 2; ++c) { ps[c] = 0.f; pq[c] = 0.f; }

    #pragma unroll
    for (int c = 0; c < 2; ++c) {
        #pragma unroll
        for (int r = 0; r < 4; ++r) {
            const int j = row0 + kseg * 4 + r;
            const _Float16 hv =
                (_Float16)(accH[c][r] + accL[c][r] * (1.f / 2048.f));
            if (j < Nout)
                out[(size_t)j * 32 + c * 16 + rrow] = hv;
            const float v = (float)hv;     // 0 for padded rows (acc==0)
            ps[c] += v;
            pq[c] += v * v;
        }
    }
    // reduce over the 4 kseg lanes sharing a column
    #pragma unroll
    for (int off = 16; off < 64; off <<= 1) {
        #pragma unroll
        for (int c = 0; c < 2; ++c) {
            ps[c] += __shfl_xor(ps[c], off);
            pq[c] += __shfl_xor(pq[c], off);
        }
    }
    __syncthreads();
    if (lane < 16) {
        #pragma unroll
        for (int c = 0; c < 2; ++c) {
            atomicAdd(&bsum[0][c * 16 + rrow], ps[c]);
            atomicAdd(&bsum[1][c * 16 + rrow], pq[c]);
        }
    }
    __syncthreads();
    if (tid < 32) {
        atomicAdd(&sums[tid], bsum[0][tid]);
        atomicAdd(&sums[32 + tid], bsum[1][tid]);
    }
}

// ---------------------------------------------------------------------------
// MFMA sparse conv (UNGROUPED, raw map): NTILE 16-row tiles per wave.
// BN pass-1 fused into the epilogue.
// ---------------------------------------------------------------------------
template<int CIN, int CINA, int COUT, int NTILE>
__global__ __launch_bounds__(256)
void sconv_mf(const _Float16* __restrict__ xA, const _Float16* __restrict__ xB,
              const _Float16* __restrict__ Wm, const int* __restrict__ map,
              int Nout, _Float16* __restrict__ out,
              const _Float16* __restrict__ zrh, float* __restrict__ sums)
{
    constexpr int CINB = CIN - CINA;
    constexpr int NT = CIN / 32;
    constexpr int NC = COUT / 16;
    constexpr int RPW = NTILE * 16;
    static_assert(CINA % 32 == 0, "CINA must be a multiple of 32");
    const int tid  = threadIdx.x;
    const int lane = tid & 63;
    const int wave = tid >> 6;
    const int row0 = (blockIdx.x * 4 + wave) * RPW;

    __shared__ int smap[4][RPW][28];
    __shared__ float bsum[2][COUT];

    if (tid < COUT) { bsum[0][tid] = 0.f; bsum[1][tid] = 0.f; }

    int mv[RPW];
    #pragma unroll
    for (int r = 0; r < RPW; ++r) {
        const int j = row0 + r;
        mv[r] = (lane < 27 && j < Nout) ? map[(size_t)lane * Nout + j] : -1;
    }
    bool anyv = false;
    #pragma unroll
    for (int r = 0; r < RPW; ++r) {
        if (lane < 27) smap[wave][r][lane] = mv[r];
        anyv |= (mv[r] >= 0);
    }
    unsigned long long act = __ballot(anyv) & 0x7FFFFFFull;

    f32x4 acc[NTILE][NC];
    #pragma unroll
    for (int tt = 0; tt < NTILE; ++tt)
        #pragma unroll
        for (int c = 0; c < NC; ++c) acc[tt][c] = (f32x4){0.f, 0.f, 0.f, 0.f};

    const int rrow = lane & 15;
    const int kseg = lane >> 4;

    auto loada = [&](int k, h8 a[NTILE][NT]) {
        #pragma unroll
        for (int tt = 0; tt < NTILE; ++tt) {
            const int m = smap[wave][tt * 16 + rrow][k];
            #pragma unroll
            for (int t = 0; t < NT; ++t) {
                const int cin0 = t * 32 + kseg * 8;
                const _Float16* pa;
                if (m >= 0) {
                    if (CINB > 0 && t * 32 >= CINA)
                        pa = xB + (size_t)m * CINB + (cin0 - CINA);
                    else
                        pa = xA + (size_t)m * CINA + cin0;
                } else {
                    pa = zrh;
                }
                a[tt][t] = *(const h8*)pa;
            }
        }
    };
    auto compute = [&](int k, h8 a[NTILE][NT]) {
        const _Float16* Wk = Wm + ((size_t)k * NT * NC * 64 + lane) * 8;
        #pragma unroll
        for (int t = 0; t < NT; ++t) {
            #pragma unroll
            for (int c = 0; c < NC; ++c) {
                const h8 b = *(const h8*)(Wk + (size_t)(t * NC + c) * 64 * 8);
                #pragma unroll
                for (int tt = 0; tt < NTILE; ++tt)
                    acc[tt][c] = __builtin_amdgcn_mfma_f32_16x16x32_f16(a[tt][t], b, acc[tt][c], 0, 0, 0);
            }
        }
    };

    h8 aC[NTILE][NT], aN[NTILE][NT];
    int kC = -1;
    if (act) {
        kC = (int)__builtin_ctzll(act);
        act &= act - 1;
        loada(kC, aC);
    }
    while (kC >= 0) {
        int kN = -1;
        if (act) {
            kN = (int)__builtin_ctzll(act);
            act &= act - 1;
            loada(kN, aN);
        }
        compute(kC, aC);
        #pragma unroll
        for (int tt = 0; tt < NTILE; ++tt)
            #pragma unroll
            for (int t = 0; t < NT; ++t) aC[tt][t] = aN[tt][t];
        kC = kN;
    }

    float ps[NC], pq[NC];
    #pragma unroll
    for (int c = 0; c < NC; ++c) { ps[c] = 0.f; pq[c] = 0.f; }

    #pragma unroll
    for (int tt = 0; tt < NTILE; ++tt) {
        #pragma unroll
        for (int c = 0; c < NC; ++c) {
            #pragma unroll
            for (int r = 0; r < 4; ++r) {
                const int j = row0 + tt * 16 + kseg * 4 + r;
                const _Float16 hv = (_Float16)acc[tt][c][r];
                if (j < Nout)
                    out[(size_t)j * COUT + c * 16 + rrow] = hv;
                const float v = (float)hv;  // 0 for padded rows
                ps[c] += v;
                pq[c] += v * v;
            }
        }
    }
    #pragma unroll
    for (int off = 16; off < 64; off <<= 1) {
        #pragma unroll
        for (int c = 0; c < NC; ++c) {
            ps[c] += __shfl_xor(ps[c], off);
            pq[c] += __shfl_xor(pq[c], off);
        }
    }
    __syncthreads();
    if (lane < 16) {
        #pragma unroll
        for (int c = 0; c < NC; ++c) {
            atomicAdd(&bsum[0][c * 16 + rrow], ps[c]);
            atomicAdd(&bsum[1][c * 16 + rrow], pq[c]);
        }
    }
    __syncthreads();
    if (tid < COUT) {
        atomicAdd(&sums[tid], bsum[0][tid]);
        atomicAdd(&sums[COUT + tid], bsum[1][tid]);
    }
}

// ---------------------------------------------------------------------------
// MFMA sparse conv (GROUPED, COMPACT order): 32 order slots/wave, two
// 16-row tiles. BN pass-1 fused; dead waves no longer early-return (barrier
// safety) -- they run an empty k-loop and contribute zero sums.
// ---------------------------------------------------------------------------
template<int CIN, int CINA, int COUT>
__global__ __launch_bounds__(256)
void sconv_mf_g(const _Float16* __restrict__ xA, const _Float16* __restrict__ xB,
                const _Float16* __restrict__ Wm, const int* __restrict__ mapT,
                const int* __restrict__ order, int Nout,
                _Float16* __restrict__ out, const _Float16* __restrict__ zrh,
                float* __restrict__ sums)
{
    constexpr int CINB = CIN - CINA;
    constexpr int NT = CIN / 32;
    constexpr int NC = COUT / 16;
    static_assert(CINA % 32 == 0, "CINA must be a multiple of 32");
    const int tid  = threadIdx.x;
    const int lane = tid & 63;
    const int wave = tid >> 6;
    const int wrow0 = (blockIdx.x * 4 + wave) * 32;

    __shared__ int sjr[4][32];
    __shared__ int smap[4][32][28];
    __shared__ float bsum[2][COUT];

    if (tid < COUT) { bsum[0][tid] = 0.f; bsum[1][tid] = 0.f; }

    int jreg = -1;
    if (lane < 32) {
        const int idx = wrow0 + lane;
        if (idx < Nout) jreg = order[idx];
    }
    if (lane < 32) sjr[wave][lane] = jreg;   // epilogue indexing only

    int mv[32];
    #pragma unroll
    for (int r = 0; r < 32; ++r) {
        const int jr = __shfl(jreg, r);
        mv[r] = (jr >= 0 && lane < 27) ? mapT[(size_t)jr * 32 + lane] : -1;
    }
    bool anyv = false;
    #pragma unroll
    for (int r = 0; r < 32; ++r) {
        if (lane < 27) smap[wave][r][lane] = mv[r];
        anyv |= (mv[r] >= 0);
    }
    unsigned long long act = __ballot(anyv) & 0x7FFFFFFull;

    f32x4 acc[2][NC];
    #pragma unroll
    for (int tt = 0; tt < 2; ++tt)
        #pragma unroll
        for (int c = 0; c < NC; ++c) acc[tt][c] = (f32x4){0.f, 0.f, 0.f, 0.f};

    const int rrow = lane & 15;
    const int kseg = lane >> 4;

    auto loada = [&](int k, h8 a[2][NT]) {
        #pragma unroll
        for (int tt = 0; tt < 2; ++tt) {
            const int m = smap[wave][tt * 16 + rrow][k];
            #pragma unroll
            for (int t = 0; t < NT; ++t) {
                const int cin0 = t * 32 + kseg * 8;
                const _Float16* pa;
                if (m >= 0) {
                    if (CINB > 0 && t * 32 >= CINA)
                        pa = xB + (size_t)m * CINB + (cin0 - CINA);
                    else
                        pa = xA + (size_t)m * CINA + cin0;
                } else {
                    pa = zrh;
                }
                a[tt][t] = *(const h8*)pa;
            }
        }
    };
    auto compute = [&](int k, h8 a[2][NT]) {
        const _Float16* Wk = Wm + ((size_t)k * NT * NC * 64 + lane) * 8;
        #pragma unroll
        for (int t = 0; t < NT; ++t) {
            #pragma unroll
            for (int c = 0; c < NC; ++c) {
                const h8 b = *(const h8*)(Wk + (size_t)(t * NC + c) * 64 * 8);
                acc[0][c] = __builtin_amdgcn_mfma_f32_16x16x32_f16(a[0][t], b, acc[0][c], 0, 0, 0);
                acc[1][c] = __builtin_amdgcn_mfma_f32_16x16x32_f16(a[1][t], b, acc[1][c], 0, 0, 0);
            }
        }
    };

    h8 aC[2][NT], aN[2][NT];
    int kC = -1;
    if (act) {
        kC = (int)__builtin_ctzll(act);
        act &= act - 1;
        loada(kC, aC);
    }
    while (kC >= 0) {
        int kN = -1;
        if (act) {
            kN = (int)__builtin_ctzll(act);
            act &= act - 1;
            loada(kN, aN);
        }
        compute(kC, aC);
        #pragma unroll
        for (int tt = 0; tt < 2; ++tt)
            #pragma unroll
            for (int t = 0; t < NT; ++t) aC[tt][t] = aN[tt][t];
        kC = kN;
    }

    float ps[NC], pq[NC];
    #pragma unroll
    for (int c = 0; c < NC; ++c) { ps[c] = 0.f; pq[c] = 0.f; }

    #pragma unroll
    for (int tt = 0; tt < 2; ++tt) {
        #pragma unroll
        for (int c = 0; c < NC; ++c) {
            #pragma unroll
            for (int r = 0; r < 4; ++r) {
                const int j = sjr[wave][tt * 16 + kseg * 4 + r];
                const _Float16 hv = (_Float16)acc[tt][c][r];
                if (j >= 0)
                    out[(size_t)j * COUT + c * 16 + rrow] = hv;
                const float v = (float)hv;  // 0 for dead slots (acc==0)
                ps[c] += v;
                pq[c] += v * v;
            }
        }
    }
    #pragma unroll
    for (int off = 16; off < 64; off <<= 1) {
        #pragma unroll
        for (int c = 0; c < NC; ++c) {
            ps[c] += __shfl_xor(ps[c], off);
            pq[c] += __shfl_xor(pq[c], off);
        }
    }
    __syncthreads();
    if (lane < 16) {
        #pragma unroll
        for (int c = 0; c < NC; ++c) {
            atomicAdd(&bsum[0][c * 16 + rrow], ps[c]);
            atomicAdd(&bsum[1][c * 16 + rrow], pq[c]);
        }
    }
    __syncthreads();
    if (tid < COUT) {
        atomicAdd(&sums[tid], bsum[0][tid]);
        atomicAdd(&sums[COUT + tid], bsum[1][tid]);
    }
}

// ---------------------------------------------------------------------------
// conv0t GATHER: 2-k pipeline + vectorized loads + XCD swizzle (kept).
// ---------------------------------------------------------------------------
__global__ __launch_bounds__(256)
void sconv0t(const _Float16* __restrict__ d1, const _Float16* __restrict__ s1,
             const float* __restrict__ W /*[27,96,2]*/,
             const int* __restrict__ map, int N, float* __restrict__ out,
             const _Float16* __restrict__ zrh)
{
    const int tid  = threadIdx.x;
    const int lane = tid & 63;
    const int l32  = tid & 31;
    const int bid  = xcd_swz(blockIdx.x, gridDim.x);
    const int j    = bid * 8 + (tid >> 5);

    int mk = (l32 < 27 && j < N) ? map[(size_t)l32 * N + j] : -1;
    const unsigned long long bal = __ballot(mk >= 0);
    unsigned int act = (unsigned int)((bal | (bal >> 32)) & 0x7FFFFFFu);

    float a0 = 0.f, a1 = 0.f;
    while (act) {
        const int k1 = (int)__builtin_ctz(act);
        act &= act - 1;
        int k2 = -1;
        if (act) { k2 = (int)__builtin_ctz(act); act &= act - 1; }
        const int k2s = (k2 >= 0) ? k2 : k1;

        const int m1 = __shfl(mk, (lane & 32) + k1);
        int m2 = __shfl(mk, (lane & 32) + k2s);
        if (k2 < 0) m2 = -1;

        // issue ALL gathers before any FMA
        const _Float16* p1a = (m1 >= 0) ? (d1 + (size_t)m1 * 64) : zrh;
        const _Float16* p1b = (m1 >= 0) ? (s1 + (size_t)m1 * 32) : zrh;
        const _Float16* p2a = (m2 >= 0) ? (d1 + (size_t)m2 * 64) : zrh;
        const _Float16* p2b = (m2 >= 0) ? (s1 + (size_t)m2 * 32) : zrh;
        const h2 xa1 = *(const h2*)(p1a + 2 * l32);
        const float xs1 = (float)p1b[l32];
        const h2 xa2 = *(const h2*)(p2a + 2 * l32);
        const float xs2 = (float)p2b[l32];

        const f4 wa1 = *(const f4*)(W + (size_t)k1 * 192 + 4 * l32);
        const f2 ws1 = *(const f2*)(W + (size_t)k1 * 192 + 128 + 2 * l32);
        const f4 wa2 = *(const f4*)(W + (size_t)k2s * 192 + 4 * l32);
        const f2 ws2 = *(const f2*)(W + (size_t)k2s * 192 + 128 + 2 * l32);

        a0 = fmaf((float)xa1[0], wa1[0], a0);
        a1 = fmaf((float)xa1[0], wa1[1], a1);
        a0 = fmaf((float)xa1[1], wa1[2], a0);
        a1 = fmaf((float)xa1[1], wa1[3], a1);
        a0 = fmaf(xs1, ws1[0], a0);
        a1 = fmaf(xs1, ws1[1], a1);

        a0 = fmaf((float)xa2[0], wa2[0], a0);
        a1 = fmaf((float)xa2[0], wa2[1], a1);
        a0 = fmaf((float)xa2[1], wa2[2], a0);
        a1 = fmaf((float)xa2[1], wa2[3], a1);
        a0 = fmaf(xs2, ws2[0], a0);
        a1 = fmaf(xs2, ws2[1], a1);
    }
    #pragma unroll
    for (int off = 1; off < 32; off <<= 1) {
        a0 += __shfl_xor(a0, off, 32);
        a1 += __shfl_xor(a1, off, 32);
    }
    if (l32 == 0 && j < N) {
        out[(size_t)j * 2 + 0] = a0;
        out[(size_t)j * 2 + 1] = a1;
    }
}

// ---------------------------------------------------------------------------
// BN pass 2, VECTORIZED.
// ---------------------------------------------------------------------------
template<int C>
__global__ __launch_bounds__(256)
void bn_apply_v(_Float16* __restrict__ x, int N,
                const float* __restrict__ sums,
                const float* __restrict__ g, const float* __restrict__ b)
{
    constexpr int CV = C / 8;
    const size_t total  = (size_t)N * CV;
    const size_t stride = (size_t)gridDim.x * 256;   // multiple of CV
    const size_t gid    = (size_t)blockIdx.x * 256 + threadIdx.x;
    const int phase = (int)(gid % CV);

    const float invN = 1.0f / (float)N;
    float sc[8], sh[8];
    #pragma unroll
    for (int u = 0; u < 8; ++u) {
        const int c = phase * 8 + u;
        const float mean = sums[c] * invN;
        float var = sums[C + c] * invN - mean * mean;
        var = fmaxf(var, 0.f);
        sc[u] = g[c] * rsqrtf(var + BN_EPS);
        sh[u] = b[c] - mean * sc[u];
    }

    for (size_t v = gid; v < total; v += stride) {
        h8 hv = *(h8*)(x + v * 8);
        #pragma unroll
        for (int u = 0; u < 8; ++u) {
            const float f = fmaf((float)hv[u], sc[u], sh[u]);
            hv[u] = (_Float16)(f > 0.f ? f : 0.f);
        }
        *(h8*)(x + v * 8) = hv;
    }
}

// ---------------------------------------------------------------------------
extern "C" void kernel_launch(void* const* d_in, const int* in_sizes, int n_in,
                              void* d_out, int out_size, void* d_ws, size_t ws_size,
                              hipStream_t stream)
{
    const float* feats = (const float*)d_in[0];
    const float* W0  = (const float*)d_in[1];
    const float* g0  = (const float*)d_in[2];
    const float* b0  = (const float*)d_in[3];
    const float* W1  = (const float*)d_in[4];
    const float* g1  = (const float*)d_in[5];
    const float* b1  = (const float*)d_in[6];
    const float* W2  = (const float*)d_in[7];
    const float* g2  = (const float*)d_in[8];
    const float* b2  = (const float*)d_in[9];
    const float* W2t = (const float*)d_in[10];
    const float* g2t = (const float*)d_in[11];
    const float* b2t = (const float*)d_in[12];
    const float* W1t = (const float*)d_in[13];
    const float* g1t = (const float*)d_in[14];
    const float* b1t = (const float*)d_in[15];
    const float* W0t = (const float*)d_in[16];
    const int* map0  = (const int*)d_in[17];
    const int* map1  = (const int*)d_in[18];
    const int* map2  = (const int*)d_in[19];
    const int* map2t = (const int*)d_in[20];
    const int* map1t = (const int*)d_in[21];
    const int* map0t = (const int*)d_in[22];

    const int N0 = in_sizes[0] / 16;
    const int N1 = in_sizes[18] / 27;
    const int N2 = in_sizes[19] / 27;

    float* ws = (float*)d_ws;
    float* sums  = ws;          // 704 floats of BN accumulators
    float* sums0 = sums;        // 2*32
    float* sums1 = sums + 64;   // 2*64
    float* sums2 = sums + 192;  // 2*128
    float* sums3 = sums + 448;  // 2*64
    float* sums4 = sums + 576;  // 2*64
    float* zrow  = sums + 704;  // 128 zeroed floats (fp32 & f16 zero rows)
    int*   gcnt  = (int*)(zrow + 128);  // 64 ints: {cnt2t[9],cur2t[9]} @0/16, {cnt1t[9],cur1t[9]} @32/48
    _Float16* Wm0h = (_Float16*)(gcnt + 64);    // 27*2*32*8 f16 (paired MFMA)
    _Float16* Wh1  = Wm0h + 27 * 2 * 32 * 8;    // 27*32*64  (MFMA layout)
    _Float16* Wh2  = Wh1 + 27 * 32 * 64;        // 27*64*128  (MFMA layout)
    _Float16* Wh2t = Wh2 + 27 * 64 * 128;       // 27*128*64  (MFMA layout)
    _Float16* Wh1t = Wh2t + 27 * 128 * 64;      // 27*128*64  (MFMA layout)
    _Float16* y0 = Wh1t + 27 * 128 * 64;        // [N0,32]  s1
    _Float16* y1 = y0 + (size_t)N0 * 32;        // [N1,64]  s2
    _Float16* y2 = y1 + (size_t)N1 * 64;        // [N2,128] s4
    _Float16* y3 = y2 + (size_t)N2 * 128;       // [N1,64]  d2
    _Float16* y4 = y3 + (size_t)N1 * 64;        // [N0,64]  d1
    int* mapT = (int*)(y4 + (size_t)N0 * 64);   // [Nmax,32] transposed map
    int* orderA = mapT + (size_t)N0 * 32;       // [N1] compact block2_tr order
    int* orderB = orderA + N1;                  // [N0] compact block1_tr order
    unsigned char* clsb = (unsigned char*)(orderB + N0);  // [Nmax] class bytes
    const _Float16* zrh = (const _Float16*)zrow;

    (void)hipMemsetAsync(sums, 0, (704 + 128 + 64) * sizeof(float), stream);

    // weight transforms (tiny)
    wtrans_mf0<<<(27 * 2 * 32 + 255) / 256, 256, 0, stream>>>(W0, Wm0h);
    wtrans_mf<32, 64><<<(27 * 1 * 4 * 64 + 255) / 256, 256, 0, stream>>>(W1, Wh1);
    wtrans_mf<64, 128><<<(27 * 2 * 8 * 64 + 255) / 256, 256, 0, stream>>>(W2, Wh2);
    wtrans_mf<128, 64><<<(27 * 4 * 4 * 64 + 255) / 256, 256, 0, stream>>>(W2t, Wh2t);
    wtrans_mf<128, 64><<<(27 * 4 * 4 * 64 + 255) / 256, 256, 0, stream>>>(W1t, Wh1t);

    // block0: feats -> y0, BN pass-1 fused into epilogue
    sconv_mf0<<<(N0 + 63) / 64, 256, 0, stream>>>(
        feats, Wm0h, map0, N0, y0, zrow, sums0);
    bn_apply_v<32><<<1024, 256, 0, stream>>>(y0, N0, sums0, g0, b0);

    // block1: MFMA ungrouped, 32 rows/wave, fused BN reduce
    sconv_mf<32, 32, 64, 2><<<(N1 + 127) / 128, 256, 0, stream>>>(
        y0, nullptr, Wh1, map1, N1, y1, zrh, sums1);
    bn_apply_v<64><<<1024, 256, 0, stream>>>(y1, N1, sums1, g1, b1);

    // block2: MFMA, 16 rows/wave, fused BN reduce
    sconv_mf<64, 64, 128, 1><<<(N2 + 63) / 64, 256, 0, stream>>>(
        y1, nullptr, Wh2, map2, N2, y2, zrh, sums2);
    bn_apply_v<128><<<1024, 256, 0, stream>>>(y2, N2, sums2, g2, b2);

    // block2_tr: parity-grouped MFMA on a COMPACT order, fused BN reduce
    map_transpose_cls<<<(N1 + 255) / 256, 256, 0, stream>>>(
        map2t, N1, mapT, clsb, gcnt);
    scatter_compact<<<(N1 + 255) / 256, 256, 0, stream>>>(
        clsb, N1, gcnt, gcnt + 16, orderA);
    sconv_mf_g<128, 128, 64><<<(N1 + 127) / 128, 256, 0, stream>>>(
        y2, nullptr, Wh2t, mapT, orderA, N1, y3, zrh, sums3);
    bn_apply_v<64><<<1024, 256, 0, stream>>>(y3, N1, sums3, g2t, b2t);

    // block1_tr: parity-grouped MFMA on a COMPACT order, fused BN reduce
    map_transpose_cls<<<(N0 + 255) / 256, 256, 0, stream>>>(
        map1t, N0, mapT, clsb, gcnt + 32);
    scatter_compact<<<(N0 + 255) / 256, 256, 0, stream>>>(
        clsb, N0, gcnt + 32, gcnt + 48, orderB);
    sconv_mf_g<128, 64, 64><<<(N0 + 127) / 128, 256, 0, stream>>>(
        y3, y1, Wh1t, mapT, orderB, N0, y4, zrh, sums4);
    bn_apply_v<64><<<1024, 256, 0, stream>>>(y4, N0, sums4, g1t, b1t);

    // block0_tr: gather conv (2-k pipelined, vectorized, XCD-swizzled)
    sconv0t<<<(N0 + 7) / 8, 256, 0, stream>>>(y4, y0, W0t, map0t, N0,
                                              (float*)d_out, zrh);
}

// Round 19
// 630.516 us; speedup vs baseline: 1.0459x; 1.0459x over previous
//
#include <hip/hip_runtime.h>
#include <cstddef>
#include <cstdint>

#define BN_EPS 1e-5f

typedef float f2 __attribute__((ext_vector_type(2)));
typedef float f4 __attribute__((ext_vector_type(4)));
typedef float f32x4 __attribute__((ext_vector_type(4)));
typedef _Float16 h2 __attribute__((ext_vector_type(2)));
typedef _Float16 h8 __attribute__((ext_vector_type(8)));

// ---------------------------------------------------------------------------
// Bijective XCD-chunked block swizzle. Kept ONLY in sconv0t (helps there:
// FETCH 92->31MB; regressed the MFMA convs when applied to them).
// ---------------------------------------------------------------------------
__device__ __forceinline__ int xcd_swz(int bid, int nwg)
{
    const int q = nwg >> 3, r = nwg & 7;
    const int xcd = bid & 7, idx = bid >> 3;
    const int base = (xcd < r) ? xcd * (q + 1) : r * (q + 1) + (xcd - r) * q;
    return base + idx;
}

// ---------------------------------------------------------------------------
// MFMA weight transform: W[27][CIN][COUT] fp32 -> B-fragment layout f16.
// ---------------------------------------------------------------------------
template<int CIN, int COUT>
__global__ __launch_bounds__(256)
void wtrans_mf(const float* __restrict__ W, _Float16* __restrict__ Wm)
{
    constexpr int NT = CIN / 32;
    constexpr int NC = COUT / 16;
    const int t = blockIdx.x * 256 + threadIdx.x;
    constexpr int TOTAL = 27 * NT * NC * 64;
    if (t >= TOTAL) return;
    const int lane = t & 63;
    int rest = t >> 6;
    const int ct = rest % NC; rest /= NC;
    const int tt = rest % NT;
    const int k  = rest / NT;
    const int cin0 = tt * 32 + (lane >> 4) * 8;
    const int co   = ct * 16 + (lane & 15);
    h8 v;
    #pragma unroll
    for (int u = 0; u < 8; ++u)
        v[u] = (_Float16)W[((size_t)k * CIN + cin0 + u) * COUT + co];
    *(h8*)(Wm + (size_t)t * 8) = v;
}

// ---------------------------------------------------------------------------
// conv0 MFMA weight transform (CIN=16, COUT=32, k-PAIRED).
// ---------------------------------------------------------------------------
__global__ __launch_bounds__(256)
void wtrans_mf0(const float* __restrict__ W, _Float16* __restrict__ Wm0)
{
    const int t = blockIdx.x * 256 + threadIdx.x;
    constexpr int TOTAL = 27 * 2 * 32;
    if (t >= TOTAL) return;
    const int co = t % 32;
    const int s  = (t / 32) % 2;
    const int k  = t / 64;
    h8 v;
    #pragma unroll
    for (int u = 0; u < 8; ++u)
        v[u] = (_Float16)W[((size_t)k * 16 + s * 8 + u) * 32 + co];
    *(h8*)(Wm0 + (size_t)t * 8) = v;
}

// ---------------------------------------------------------------------------
// Pass A: map transpose + parity-class byte + LDS-aggregated histogram.
// ---------------------------------------------------------------------------
__global__ __launch_bounds__(256)
void map_transpose_cls(const int* __restrict__ map, int Nout,
                       int* __restrict__ mapT, unsigned char* __restrict__ cls,
                       int* __restrict__ counts)
{
    __shared__ int s[256][28];
    __shared__ int hist[9];
    const int tid  = threadIdx.x;
    const int base = blockIdx.x * 256;
    const int j    = base + tid;
    if (tid < 9) hist[tid] = 0;
    for (int k = 0; k < 27; ++k)
        s[tid][k] = (j < Nout) ? map[(size_t)k * Nout + j] : -1;
    __syncthreads();
    for (int i = tid; i < 256 * 32; i += 256) {
        const int r = i >> 5, c = i & 31;
        if (base + r < Nout)
            mapT[(size_t)(base + r) * 32 + c] = (c < 27) ? s[r][c] : -1;
    }
    if (j < Nout) {
        int c9 = 8;
        #pragma unroll 1
        for (int k = 0; k < 27; ++k) {
            if (s[tid][k] >= 0) {
                const int dz = k % 3, dy = (k / 3) % 3, dx = k / 9;
                c9 = ((dx != 1) << 2) | ((dy != 1) << 1) | (int)(dz != 1);
                break;
            }
        }
        cls[j] = (unsigned char)c9;
        atomicAdd(&hist[c9], 1);
    }
    __syncthreads();
    if (tid < 9 && hist[tid] > 0)
        atomicAdd(&counts[tid], hist[tid]);
}

// ---------------------------------------------------------------------------
// Pass C: COMPACT class-grouped scatter (dense order[], no dead slots).
// ---------------------------------------------------------------------------
__global__ __launch_bounds__(256)
void scatter_compact(const unsigned char* __restrict__ cls, int Nout,
                     const int* __restrict__ counts, int* __restrict__ cursors,
                     int* __restrict__ order)
{
    __shared__ int hist[9], basec[9];
    const int tid = threadIdx.x;
    const int j   = blockIdx.x * 256 + tid;
    if (tid < 9) hist[tid] = 0;
    const int c9 = (j < Nout) ? (int)cls[j] : -1;
    __syncthreads();
    int lpos = 0;
    if (c9 >= 0) lpos = atomicAdd(&hist[c9], 1);
    __syncthreads();
    if (tid < 9 && hist[tid] > 0)
        basec[tid] = atomicAdd(&cursors[tid], hist[tid]);
    __syncthreads();
    if (c9 >= 0) {
        int offs = 0;
        #pragma unroll
        for (int c = 0; c < 9; ++c)
            if (c < c9) offs += counts[c];
        order[offs + basec[c9] + lpos] = j;
    }
}

// ---------------------------------------------------------------------------
// conv0 MFMA (CIN=16 fp32 in, COUT=32, k-PAIRED, compensated hi/lo).
// Round-19: round-18's fused-BN epilogue REVERTED -- the post-k-loop
// __syncthreads coupled waves with divergent k-union lengths and cost
// ~35us on this kernel alone; standalone bn_reduce_v is cheaper.
// ---------------------------------------------------------------------------
__global__ __launch_bounds__(256)
void sconv_mf0(const float* __restrict__ x, const _Float16* __restrict__ Wm0,
               const int* __restrict__ map, int Nout,
               _Float16* __restrict__ out, const float* __restrict__ zrow)
{
    const int lane = threadIdx.x & 63;
    const int wave = threadIdx.x >> 6;
    const int row0 = (blockIdx.x * 4 + wave) * 16;

    __shared__ int smap[4][16][28];

    int mk[16];
    bool anyv = false;
    #pragma unroll
    for (int r = 0; r < 16; ++r) {
        const int j = row0 + r;
        mk[r] = (lane < 27 && j < Nout) ? map[(size_t)lane * Nout + j] : -1;
        anyv |= (mk[r] >= 0);
    }
    unsigned long long act = __ballot(anyv);

    if (lane < 27) {
        #pragma unroll
        for (int r = 0; r < 16; ++r)
            smap[wave][r][lane] = mk[r];
    }

    f32x4 accH[2], accL[2];
    #pragma unroll
    for (int c = 0; c < 2; ++c) {
        accH[c] = (f32x4){0.f, 0.f, 0.f, 0.f};
        accL[c] = (f32x4){0.f, 0.f, 0.f, 0.f};
    }

    const int rrow = lane & 15;   // A row / D col
    const int kseg = lane >> 4;
    const int half = kseg & 1;    // cin half: 0 -> 0..7, 1 -> 8..15
    const bool useK1 = (kseg < 2);

    while (act) {
        const int k1 = (int)__builtin_ctzll(act);
        act &= act - 1;
        int k2 = -1;
        if (act) {
            k2 = (int)__builtin_ctzll(act);
            act &= act - 1;
        }
        const int ks = useK1 ? k1 : k2;
        int m = -1;
        if (ks >= 0) m = smap[wave][rrow][ks];

        const float* px = (m >= 0) ? (x + (size_t)m * 16 + half * 8)
                                   : (zrow + half * 8);
        const f4 x0 = *(const f4*)px;
        const f4 x1 = *(const f4*)(px + 4);
        h8 aH, aL;
        #pragma unroll
        for (int u = 0; u < 4; ++u) {
            const float v0 = x0[u], v1 = x1[u];
            const _Float16 h0 = (_Float16)v0;
            const _Float16 h1 = (_Float16)v1;
            aH[u]     = h0;
            aH[u + 4] = h1;
            aL[u]     = (_Float16)((v0 - (float)h0) * 2048.f);
            aL[u + 4] = (_Float16)((v1 - (float)h1) * 2048.f);
        }

        const int ksafe = (ks >= 0) ? ks : 0;   // a==0 makes b irrelevant
        const _Float16* wb = Wm0 + ((size_t)(ksafe * 2 + half) * 32) * 8;
        #pragma unroll
        for (int c = 0; c < 2; ++c) {
            const h8 b = *(const h8*)(wb + (size_t)(c * 16 + rrow) * 8);
            accH[c] = __builtin_amdgcn_mfma_f32_16x16x32_f16(aH, b, accH[c], 0, 0, 0);
            accL[c] = __builtin_amdgcn_mfma_f32_16x16x32_f16(aL, b, accL[c], 0, 0, 0);
        }
    }

    #pragma unroll
    for (int c = 0; c < 2; ++c) {
        #pragma unroll
        for (int r = 0; r < 4; ++r) {
            const int j = row0 + kseg * 4 + r;
            if (j < Nout)
                out[(size_t)j * 32 + c * 16 + rrow] =
                    (_Float16)(accH[c][r] + accL[c][r] * (1.f / 2048.f));
        }
    }
}

// ---------------------------------------------------------------------------
// MFMA sparse conv (UNGROUPED, raw map): NTILE 16-row tiles per wave sharing
// one k-union and B fragments. block2 uses NTILE=1 (16 rows/wave) for
// latency hiding with zero A-traffic duplication.
// ---------------------------------------------------------------------------
template<int CIN, int CINA, int COUT, int NTILE>
__global__ __launch_bounds__(256)
void sconv_mf(const _Float16* __restrict__ xA, const _Float16* __restrict__ xB,
              const _Float16* __restrict__ Wm, const int* __restrict__ map,
              int Nout, _Float16* __restrict__ out,
              const _Float16* __restrict__ zrh)
{
    constexpr int CINB = CIN - CINA;
    constexpr int NT = CIN / 32;
    constexpr int NC = COUT / 16;
    constexpr int RPW = NTILE * 16;
    static_assert(CINA % 32 == 0, "CINA must be a multiple of 32");
    const int lane = threadIdx.x & 63;
    const int wave = threadIdx.x >> 6;
    const int row0 = (blockIdx.x * 4 + wave) * RPW;

    __shared__ int smap[4][RPW][28];

    int mv[RPW];
    #pragma unroll
    for (int r = 0; r < RPW; ++r) {
        const int j = row0 + r;
        mv[r] = (lane < 27 && j < Nout) ? map[(size_t)lane * Nout + j] : -1;
    }
    bool anyv = false;
    #pragma unroll
    for (int r = 0; r < RPW; ++r) {
        if (lane < 27) smap[wave][r][lane] = mv[r];
        anyv |= (mv[r] >= 0);
    }
    unsigned long long act = __ballot(anyv) & 0x7FFFFFFull;

    f32x4 acc[NTILE][NC];
    #pragma unroll
    for (int tt = 0; tt < NTILE; ++tt)
        #pragma unroll
        for (int c = 0; c < NC; ++c) acc[tt][c] = (f32x4){0.f, 0.f, 0.f, 0.f};

    const int rrow = lane & 15;
    const int kseg = lane >> 4;

    auto loada = [&](int k, h8 a[NTILE][NT]) {
        #pragma unroll
        for (int tt = 0; tt < NTILE; ++tt) {
            const int m = smap[wave][tt * 16 + rrow][k];
            #pragma unroll
            for (int t = 0; t < NT; ++t) {
                const int cin0 = t * 32 + kseg * 8;
                const _Float16* pa;
                if (m >= 0) {
                    if (CINB > 0 && t * 32 >= CINA)
                        pa = xB + (size_t)m * CINB + (cin0 - CINA);
                    else
                        pa = xA + (size_t)m * CINA + cin0;
                } else {
                    pa = zrh;
                }
                a[tt][t] = *(const h8*)pa;
            }
        }
    };
    auto compute = [&](int k, h8 a[NTILE][NT]) {
        const _Float16* Wk = Wm + ((size_t)k * NT * NC * 64 + lane) * 8;
        #pragma unroll
        for (int t = 0; t < NT; ++t) {
            #pragma unroll
            for (int c = 0; c < NC; ++c) {
                const h8 b = *(const h8*)(Wk + (size_t)(t * NC + c) * 64 * 8);
                #pragma unroll
                for (int tt = 0; tt < NTILE; ++tt)
                    acc[tt][c] = __builtin_amdgcn_mfma_f32_16x16x32_f16(a[tt][t], b, acc[tt][c], 0, 0, 0);
            }
        }
    };

    h8 aC[NTILE][NT], aN[NTILE][NT];
    int kC = -1;
    if (act) {
        kC = (int)__builtin_ctzll(act);
        act &= act - 1;
        loada(kC, aC);
    }
    while (kC >= 0) {
        int kN = -1;
        if (act) {
            kN = (int)__builtin_ctzll(act);
            act &= act - 1;
            loada(kN, aN);
        }
        compute(kC, aC);
        #pragma unroll
        for (int tt = 0; tt < NTILE; ++tt)
            #pragma unroll
            for (int t = 0; t < NT; ++t) aC[tt][t] = aN[tt][t];
        kC = kN;
    }

    #pragma unroll
    for (int tt = 0; tt < NTILE; ++tt) {
        #pragma unroll
        for (int c = 0; c < NC; ++c) {
            #pragma unroll
            for (int r = 0; r < 4; ++r) {
                const int j = row0 + tt * 16 + kseg * 4 + r;
                if (j < Nout)
                    out[(size_t)j * COUT + c * 16 + rrow] = (_Float16)acc[tt][c][r];
            }
        }
    }
}

// ---------------------------------------------------------------------------
// MFMA sparse conv (GROUPED, COMPACT order): 32 order slots/wave, two
// 16-row tiles.
// ---------------------------------------------------------------------------
template<int CIN, int CINA, int COUT>
__global__ __launch_bounds__(256)
void sconv_mf_g(const _Float16* __restrict__ xA, const _Float16* __restrict__ xB,
                const _Float16* __restrict__ Wm, const int* __restrict__ mapT,
                const int* __restrict__ order, int Nout,
                _Float16* __restrict__ out, const _Float16* __restrict__ zrh)
{
    constexpr int CINB = CIN - CINA;
    constexpr int NT = CIN / 32;
    constexpr int NC = COUT / 16;
    static_assert(CINA % 32 == 0, "CINA must be a multiple of 32");
    const int lane = threadIdx.x & 63;
    const int wave = threadIdx.x >> 6;
    const int wrow0 = (blockIdx.x * 4 + wave) * 32;

    __shared__ int sjr[4][32];
    __shared__ int smap[4][32][28];

    int jreg = -1;
    if (lane < 32) {
        const int idx = wrow0 + lane;
        if (idx < Nout) jreg = order[idx];
    }
    if (!__ballot(jreg >= 0)) return;     // tail only (order is compact)
    if (lane < 32) sjr[wave][lane] = jreg;   // epilogue indexing only

    int mv[32];
    #pragma unroll
    for (int r = 0; r < 32; ++r) {
        const int jr = __shfl(jreg, r);
        mv[r] = (jr >= 0 && lane < 27) ? mapT[(size_t)jr * 32 + lane] : -1;
    }
    bool anyv = false;
    #pragma unroll
    for (int r = 0; r < 32; ++r) {
        if (lane < 27) smap[wave][r][lane] = mv[r];
        anyv |= (mv[r] >= 0);
    }
    unsigned long long act = __ballot(anyv) & 0x7FFFFFFull;

    f32x4 acc[2][NC];
    #pragma unroll
    for (int tt = 0; tt < 2; ++tt)
        #pragma unroll
        for (int c = 0; c < NC; ++c) acc[tt][c] = (f32x4){0.f, 0.f, 0.f, 0.f};

    const int rrow = lane & 15;
    const int kseg = lane >> 4;

    auto loada = [&](int k, h8 a[2][NT]) {
        #pragma unroll
        for (int tt = 0; tt < 2; ++tt) {
            const int m = smap[wave][tt * 16 + rrow][k];
            #pragma unroll
            for (int t = 0; t < NT; ++t) {
                const int cin0 = t * 32 + kseg * 8;
                const _Float16* pa;
                if (m >= 0) {
                    if (CINB > 0 && t * 32 >= CINA)
                        pa = xB + (size_t)m * CINB + (cin0 - CINA);
                    else
                        pa = xA + (size_t)m * CINA + cin0;
                } else {
                    pa = zrh;
                }
                a[tt][t] = *(const h8*)pa;
            }
        }
    };
    auto compute = [&](int k, h8 a[2][NT]) {
        const _Float16* Wk = Wm + ((size_t)k * NT * NC * 64 + lane) * 8;
        #pragma unroll
        for (int t = 0; t < NT; ++t) {
            #pragma unroll
            for (int c = 0; c < NC; ++c) {
                const h8 b = *(const h8*)(Wk + (size_t)(t * NC + c) * 64 * 8);
                acc[0][c] = __builtin_amdgcn_mfma_f32_16x16x32_f16(a[0][t], b, acc[0][c], 0, 0, 0);
                acc[1][c] = __builtin_amdgcn_mfma_f32_16x16x32_f16(a[1][t], b, acc[1][c], 0, 0, 0);
            }
        }
    };

    h8 aC[2][NT], aN[2][NT];
    int kC = -1;
    if (act) {
        kC = (int)__builtin_ctzll(act);
        act &= act - 1;
        loada(kC, aC);
    }
    while (kC >= 0) {
        int kN = -1;
        if (act) {
            kN = (int)__builtin_ctzll(act);
            act &= act - 1;
            loada(kN, aN);
        }
        compute(kC, aC);
        #pragma unroll
        for (int tt = 0; tt < 2; ++tt)
            #pragma unroll
            for (int t = 0; t < NT; ++t) aC[tt][t] = aN[tt][t];
        kC = kN;
    }

    #pragma unroll
    for (int tt = 0; tt < 2; ++tt) {
        #pragma unroll
        for (int c = 0; c < NC; ++c) {
            #pragma unroll
            for (int r = 0; r < 4; ++r) {
                const int j = sjr[wave][tt * 16 + kseg * 4 + r];
                if (j >= 0)
                    out[(size_t)j * COUT + c * 16 + rrow] = (_Float16)acc[tt][c][r];
            }
        }
    }
}

// ---------------------------------------------------------------------------
// conv0t GATHER: 2-k pipeline + vectorized loads + XCD swizzle (kept).
// ---------------------------------------------------------------------------
__global__ __launch_bounds__(256)
void sconv0t(const _Float16* __restrict__ d1, const _Float16* __restrict__ s1,
             const float* __restrict__ W /*[27,96,2]*/,
             const int* __restrict__ map, int N, float* __restrict__ out,
             const _Float16* __restrict__ zrh)
{
    const int tid  = threadIdx.x;
    const int lane = tid & 63;
    const int l32  = tid & 31;
    const int bid  = xcd_swz(blockIdx.x, gridDim.x);
    const int j    = bid * 8 + (tid >> 5);

    int mk = (l32 < 27 && j < N) ? map[(size_t)l32 * N + j] : -1;
    const unsigned long long bal = __ballot(mk >= 0);
    unsigned int act = (unsigned int)((bal | (bal >> 32)) & 0x7FFFFFFu);

    float a0 = 0.f, a1 = 0.f;
    while (act) {
        const int k1 = (int)__builtin_ctz(act);
        act &= act - 1;
        int k2 = -1;
        if (act) { k2 = (int)__builtin_ctz(act); act &= act - 1; }
        const int k2s = (k2 >= 0) ? k2 : k1;

        const int m1 = __shfl(mk, (lane & 32) + k1);
        int m2 = __shfl(mk, (lane & 32) + k2s);
        if (k2 < 0) m2 = -1;

        // issue ALL gathers before any FMA
        const _Float16* p1a = (m1 >= 0) ? (d1 + (size_t)m1 * 64) : zrh;
        const _Float16* p1b = (m1 >= 0) ? (s1 + (size_t)m1 * 32) : zrh;
        const _Float16* p2a = (m2 >= 0) ? (d1 + (size_t)m2 * 64) : zrh;
        const _Float16* p2b = (m2 >= 0) ? (s1 + (size_t)m2 * 32) : zrh;
        const h2 xa1 = *(const h2*)(p1a + 2 * l32);
        const float xs1 = (float)p1b[l32];
        const h2 xa2 = *(const h2*)(p2a + 2 * l32);
        const float xs2 = (float)p2b[l32];

        const f4 wa1 = *(const f4*)(W + (size_t)k1 * 192 + 4 * l32);
        const f2 ws1 = *(const f2*)(W + (size_t)k1 * 192 + 128 + 2 * l32);
        const f4 wa2 = *(const f4*)(W + (size_t)k2s * 192 + 4 * l32);
        const f2 ws2 = *(const f2*)(W + (size_t)k2s * 192 + 128 + 2 * l32);

        a0 = fmaf((float)xa1[0], wa1[0], a0);
        a1 = fmaf((float)xa1[0], wa1[1], a1);
        a0 = fmaf((float)xa1[1], wa1[2], a0);
        a1 = fmaf((float)xa1[1], wa1[3], a1);
        a0 = fmaf(xs1, ws1[0], a0);
        a1 = fmaf(xs1, ws1[1], a1);

        a0 = fmaf((float)xa2[0], wa2[0], a0);
        a1 = fmaf((float)xa2[0], wa2[1], a1);
        a0 = fmaf((float)xa2[1], wa2[2], a0);
        a1 = fmaf((float)xa2[1], wa2[3], a1);
        a0 = fmaf(xs2, ws2[0], a0);
        a1 = fmaf(xs2, ws2[1], a1);
    }
    #pragma unroll
    for (int off = 1; off < 32; off <<= 1) {
        a0 += __shfl_xor(a0, off, 32);
        a1 += __shfl_xor(a1, off, 32);
    }
    if (l32 == 0 && j < N) {
        out[(size_t)j * 2 + 0] = a0;
        out[(size_t)j * 2 + 1] = a1;
    }
}

// ---------------------------------------------------------------------------
// BN pass 1, VECTORIZED.
// ---------------------------------------------------------------------------
template<int C>
__global__ __launch_bounds__(256)
void bn_reduce_v(const _Float16* __restrict__ x, int N,
                 float* __restrict__ sums)
{
    constexpr int CV = C / 8;   // h8 vectors per row (4, 8, or 16)
    const int tid  = threadIdx.x;
    const int lane = tid & 63;
    const int wave = tid >> 6;
    const size_t total  = (size_t)N * CV;
    const size_t stride = (size_t)gridDim.x * 256;   // multiple of CV
    const size_t gid    = (size_t)blockIdx.x * 256 + tid;

    float s[8], s2[8];
    #pragma unroll
    for (int u = 0; u < 8; ++u) { s[u] = 0.f; s2[u] = 0.f; }

    for (size_t v = gid; v < total; v += stride) {
        const h8 hv = *(const h8*)(x + v * 8);
        #pragma unroll
        for (int u = 0; u < 8; ++u) {
            const float f = (float)hv[u];
            s[u] += f;
            s2[u] += f * f;
        }
    }

    #pragma unroll
    for (int off = CV; off < 64; off <<= 1) {
        #pragma unroll
        for (int u = 0; u < 8; ++u) {
            s[u]  += __shfl_xor(s[u], off);
            s2[u] += __shfl_xor(s2[u], off);
        }
    }

    __shared__ float shs[4][16][8];
    __shared__ float shq[4][16][8];
    if (lane < CV) {
        #pragma unroll
        for (int u = 0; u < 8; ++u) {
            shs[wave][lane][u] = s[u];
            shq[wave][lane][u] = s2[u];
        }
    }
    __syncthreads();
    if (tid < C) {
        const int ph = tid >> 3, u = tid & 7;
        float ts = 0.f, tq = 0.f;
        #pragma unroll
        for (int w = 0; w < 4; ++w) {
            ts += shs[w][ph][u];
            tq += shq[w][ph][u];
        }
        atomicAdd(&sums[tid], ts);
        atomicAdd(&sums[C + tid], tq);
    }
}

// ---------------------------------------------------------------------------
// BN pass 2, VECTORIZED.
// ---------------------------------------------------------------------------
template<int C>
__global__ __launch_bounds__(256)
void bn_apply_v(_Float16* __restrict__ x, int N,
                const float* __restrict__ sums,
                const float* __restrict__ g, const float* __restrict__ b)
{
    constexpr int CV = C / 8;
    const size_t total  = (size_t)N * CV;
    const size_t stride = (size_t)gridDim.x * 256;   // multiple of CV
    const size_t gid    = (size_t)blockIdx.x * 256 + threadIdx.x;
    const int phase = (int)(gid % CV);

    const float invN = 1.0f / (float)N;
    float sc[8], sh[8];
    #pragma unroll
    for (int u = 0; u < 8; ++u) {
        const int c = phase * 8 + u;
        const float mean = sums[c] * invN;
        float var = sums[C + c] * invN - mean * mean;
        var = fmaxf(var, 0.f);
        sc[u] = g[c] * rsqrtf(var + BN_EPS);
        sh[u] = b[c] - mean * sc[u];
    }

    for (size_t v = gid; v < total; v += stride) {
        h8 hv = *(h8*)(x + v * 8);
        #pragma unroll
        for (int u = 0; u < 8; ++u) {
            const float f = fmaf((float)hv[u], sc[u], sh[u]);
            hv[u] = (_Float16)(f > 0.f ? f : 0.f);
        }
        *(h8*)(x + v * 8) = hv;
    }
}

// ---------------------------------------------------------------------------
extern "C" void kernel_launch(void* const* d_in, const int* in_sizes, int n_in,
                              void* d_out, int out_size, void* d_ws, size_t ws_size,
                              hipStream_t stream)
{
    const float* feats = (const float*)d_in[0];
    const float* W0  = (const float*)d_in[1];
    const float* g0  = (const float*)d_in[2];
    const float* b0  = (const float*)d_in[3];
    const float* W1  = (const float*)d_in[4];
    const float* g1  = (const float*)d_in[5];
    const float* b1  = (const float*)d_in[6];
    const float* W2  = (const float*)d_in[7];
    const float* g2  = (const float*)d_in[8];
    const float* b2  = (const float*)d_in[9];
    const float* W2t = (const float*)d_in[10];
    const float* g2t = (const float*)d_in[11];
    const float* b2t = (const float*)d_in[12];
    const float* W1t = (const float*)d_in[13];
    const float* g1t = (const float*)d_in[14];
    const float* b1t = (const float*)d_in[15];
    const float* W0t = (const float*)d_in[16];
    const int* map0  = (const int*)d_in[17];
    const int* map1  = (const int*)d_in[18];
    const int* map2  = (const int*)d_in[19];
    const int* map2t = (const int*)d_in[20];
    const int* map1t = (const int*)d_in[21];
    const int* map0t = (const int*)d_in[22];

    const int N0 = in_sizes[0] / 16;
    const int N1 = in_sizes[18] / 27;
    const int N2 = in_sizes[19] / 27;

    float* ws = (float*)d_ws;
    float* sums  = ws;          // 704 floats of BN accumulators
    float* sums0 = sums;        // 2*32
    float* sums1 = sums + 64;   // 2*64
    float* sums2 = sums + 192;  // 2*128
    float* sums3 = sums + 448;  // 2*64
    float* sums4 = sums + 576;  // 2*64
    float* zrow  = sums + 704;  // 128 zeroed floats (fp32 & f16 zero rows)
    int*   gcnt  = (int*)(zrow + 128);  // 64 ints: {cnt2t[9],cur2t[9]} @0/16, {cnt1t[9],cur1t[9]} @32/48
    _Float16* Wm0h = (_Float16*)(gcnt + 64);    // 27*2*32*8 f16 (paired MFMA)
    _Float16* Wh1  = Wm0h + 27 * 2 * 32 * 8;    // 27*32*64  (MFMA layout)
    _Float16* Wh2  = Wh1 + 27 * 32 * 64;        // 27*64*128  (MFMA layout)
    _Float16* Wh2t = Wh2 + 27 * 64 * 128;       // 27*128*64  (MFMA layout)
    _Float16* Wh1t = Wh2t + 27 * 128 * 64;      // 27*128*64  (MFMA layout)
    _Float16* y0 = Wh1t + 27 * 128 * 64;        // [N0,32]  s1
    _Float16* y1 = y0 + (size_t)N0 * 32;        // [N1,64]  s2
    _Float16* y2 = y1 + (size_t)N1 * 64;        // [N2,128] s4
    _Float16* y3 = y2 + (size_t)N2 * 128;       // [N1,64]  d2
    _Float16* y4 = y3 + (size_t)N1 * 64;        // [N0,64]  d1
    int* mapT = (int*)(y4 + (size_t)N0 * 64);   // [Nmax,32] transposed map
    int* orderA = mapT + (size_t)N0 * 32;       // [N1] compact block2_tr order
    int* orderB = orderA + N1;                  // [N0] compact block1_tr order
    unsigned char* clsb = (unsigned char*)(orderB + N0);  // [Nmax] class bytes
    const _Float16* zrh = (const _Float16*)zrow;

    (void)hipMemsetAsync(sums, 0, (704 + 128 + 64) * sizeof(float), stream);

    // weight transforms (tiny)
    wtrans_mf0<<<(27 * 2 * 32 + 255) / 256, 256, 0, stream>>>(W0, Wm0h);
    wtrans_mf<32, 64><<<(27 * 1 * 4 * 64 + 255) / 256, 256, 0, stream>>>(W1, Wh1);
    wtrans_mf<64, 128><<<(27 * 2 * 8 * 64 + 255) / 256, 256, 0, stream>>>(W2, Wh2);
    wtrans_mf<128, 64><<<(27 * 4 * 4 * 64 + 255) / 256, 256, 0, stream>>>(W2t, Wh2t);
    wtrans_mf<128, 64><<<(27 * 4 * 4 * 64 + 255) / 256, 256, 0, stream>>>(W1t, Wh1t);

    // block0: feats[N0,16] fp32 -> y0[N0,32] half. MFMA k-paired hi/lo.
    sconv_mf0<<<(N0 + 63) / 64, 256, 0, stream>>>(
        feats, Wm0h, map0, N0, y0, zrow);
    bn_reduce_v<32><<<512, 256, 0, stream>>>(y0, N0, sums0);
    bn_apply_v<32><<<1024, 256, 0, stream>>>(y0, N0, sums0, g0, b0);

    // block1: MFMA ungrouped, 32 rows/wave
    sconv_mf<32, 32, 64, 2><<<(N1 + 127) / 128, 256, 0, stream>>>(
        y0, nullptr, Wh1, map1, N1, y1, zrh);
    bn_reduce_v<64><<<512, 256, 0, stream>>>(y1, N1, sums1);
    bn_apply_v<64><<<1024, 256, 0, stream>>>(y1, N1, sums1, g1, b1);

    // block2: MFMA, 16 rows/wave (2x waves for latency hiding)
    sconv_mf<64, 64, 128, 1><<<(N2 + 63) / 64, 256, 0, stream>>>(
        y1, nullptr, Wh2, map2, N2, y2, zrh);
    bn_reduce_v<128><<<512, 256, 0, stream>>>(y2, N2, sums2);
    bn_apply_v<128><<<1024, 256, 0, stream>>>(y2, N2, sums2, g2, b2);

    // block2_tr: parity-grouped MFMA on a COMPACT order (unsplit)
    map_transpose_cls<<<(N1 + 255) / 256, 256, 0, stream>>>(
        map2t, N1, mapT, clsb, gcnt);
    scatter_compact<<<(N1 + 255) / 256, 256, 0, stream>>>(
        clsb, N1, gcnt, gcnt + 16, orderA);
    sconv_mf_g<128, 128, 64><<<(N1 + 127) / 128, 256, 0, stream>>>(
        y2, nullptr, Wh2t, mapT, orderA, N1, y3, zrh);
    bn_reduce_v<64><<<512, 256, 0, stream>>>(y3, N1, sums3);
    bn_apply_v<64><<<1024, 256, 0, stream>>>(y3, N1, sums3, g2t, b2t);

    // block1_tr: parity-grouped MFMA on a COMPACT order (unsplit)
    map_transpose_cls<<<(N0 + 255) / 256, 256, 0, stream>>>(
        map1t, N0, mapT, clsb, gcnt + 32);
    scatter_compact<<<(N0 + 255) / 256, 256, 0, stream>>>(
        clsb, N0, gcnt + 32, gcnt + 48, orderB);
    sconv_mf_g<128, 64, 64><<<(N0 + 127) / 128, 256, 0, stream>>>(
        y3, y1, Wh1t, mapT, orderB, N0, y4, zrh);
    bn_reduce_v<64><<<512, 256, 0, stream>>>(y4, N0, sums4);
    bn_apply_v<64><<<1024, 256, 0, stream>>>(y4, N0, sums4, g1t, b1t);

    // block0_tr: gather conv (2-k pipelined, vectorized, XCD-swizzled)
    sconv0t<<<(N0 + 7) / 8, 256, 0, stream>>>(y4, y0, W0t, map0t, N0,
                                              (float*)d_out, zrh);
}

// Round 20
// 600.951 us; speedup vs baseline: 1.0973x; 1.0492x over previous
//
#include <hip/hip_runtime.h>
#include <cstddef>
#include <cstdint>

#define BN_EPS 1e-5f

typedef float f2 __attribute__((ext_vector_type(2)));
typedef float f4 __attribute__((ext_vector_type(4)));
typedef float f32x4 __attribute__((ext_vector_type(4)));
typedef _Float16 h2 __attribute__((ext_vector_type(2)));
typedef _Float16 h8 __attribute__((ext_vector_type(8)));

// ---------------------------------------------------------------------------
// Bijective XCD-chunked block swizzle. Kept ONLY in sconv0t (helps there:
// FETCH 92->31MB; regressed the MFMA convs when applied to them).
// ---------------------------------------------------------------------------
__device__ __forceinline__ int xcd_swz(int bid, int nwg)
{
    const int q = nwg >> 3, r = nwg & 7;
    const int xcd = bid & 7, idx = bid >> 3;
    const int base = (xcd < r) ? xcd * (q + 1) : r * (q + 1) + (xcd - r) * q;
    return base + idx;
}

// ---------------------------------------------------------------------------
// Weight-transform device bodies (round-20: all 5 transforms fused into ONE
// launch -- they are tiny and were costing 4 extra launch gaps).
// ---------------------------------------------------------------------------
template<int CIN, int COUT>
__device__ __forceinline__ void wtrans_body(const float* __restrict__ W,
                                            _Float16* __restrict__ Wm, int t)
{
    constexpr int NT = CIN / 32;
    constexpr int NC = COUT / 16;
    const int lane = t & 63;
    int rest = t >> 6;
    const int ct = rest % NC; rest /= NC;
    const int tt = rest % NT;
    const int k  = rest / NT;
    const int cin0 = tt * 32 + (lane >> 4) * 8;
    const int co   = ct * 16 + (lane & 15);
    h8 v;
    #pragma unroll
    for (int u = 0; u < 8; ++u)
        v[u] = (_Float16)W[((size_t)k * CIN + cin0 + u) * COUT + co];
    *(h8*)(Wm + (size_t)t * 8) = v;
}

__device__ __forceinline__ void wtrans0_body(const float* __restrict__ W,
                                             _Float16* __restrict__ Wm0, int t)
{
    const int co = t % 32;
    const int s  = (t / 32) % 2;
    const int k  = t / 64;
    h8 v;
    #pragma unroll
    for (int u = 0; u < 8; ++u)
        v[u] = (_Float16)W[((size_t)k * 16 + s * 8 + u) * 32 + co];
    *(h8*)(Wm0 + (size_t)t * 8) = v;
}

// TOT: mf0=1728, w1=6912, w2=27648, w2t=27648, w1t=27648 -> 91584 threads
__global__ __launch_bounds__(256)
void wtrans_all(const float* __restrict__ W0,  const float* __restrict__ W1,
                const float* __restrict__ W2,  const float* __restrict__ W2t,
                const float* __restrict__ W1t,
                _Float16* __restrict__ Wm0h, _Float16* __restrict__ Wh1,
                _Float16* __restrict__ Wh2,  _Float16* __restrict__ Wh2t,
                _Float16* __restrict__ Wh1t)
{
    int t = blockIdx.x * 256 + threadIdx.x;
    if (t < 1728) { wtrans0_body(W0, Wm0h, t); return; }
    t -= 1728;
    if (t < 6912) { wtrans_body<32, 64>(W1, Wh1, t); return; }
    t -= 6912;
    if (t < 27648) { wtrans_body<64, 128>(W2, Wh2, t); return; }
    t -= 27648;
    if (t < 27648) { wtrans_body<128, 64>(W2t, Wh2t, t); return; }
    t -= 27648;
    if (t < 27648) { wtrans_body<128, 64>(W1t, Wh1t, t); return; }
}

// ---------------------------------------------------------------------------
// Pass A body: map transpose + parity-class byte + LDS-aggregated histogram.
// ---------------------------------------------------------------------------
__device__ __forceinline__ void cls_body(const int* __restrict__ map, int Nout,
                                         int* __restrict__ mapT,
                                         unsigned char* __restrict__ cls,
                                         int* __restrict__ counts)
{
    __shared__ int s[256][28];
    __shared__ int hist[9];
    const int tid  = threadIdx.x;
    const int base = blockIdx.x * 256;
    const int j    = base + tid;
    if (tid < 9) hist[tid] = 0;
    for (int k = 0; k < 27; ++k)
        s[tid][k] = (j < Nout) ? map[(size_t)k * Nout + j] : -1;
    __syncthreads();
    for (int i = tid; i < 256 * 32; i += 256) {
        const int r = i >> 5, c = i & 31;
        if (base + r < Nout)
            mapT[(size_t)(base + r) * 32 + c] = (c < 27) ? s[r][c] : -1;
    }
    if (j < Nout) {
        int c9 = 8;
        #pragma unroll 1
        for (int k = 0; k < 27; ++k) {
            if (s[tid][k] >= 0) {
                const int dz = k % 3, dy = (k / 3) % 3, dx = k / 9;
                c9 = ((dx != 1) << 2) | ((dy != 1) << 1) | (int)(dz != 1);
                break;
            }
        }
        cls[j] = (unsigned char)c9;
        atomicAdd(&hist[c9], 1);
    }
    __syncthreads();
    if (tid < 9 && hist[tid] > 0)
        atomicAdd(&counts[tid], hist[tid]);
}

// Fused: blockIdx.y=0 -> (map2t,N1) set, 1 -> (map1t,N0) set.
__global__ __launch_bounds__(256)
void map_transpose_cls2(const int* __restrict__ mapA, int NA,
                        int* __restrict__ mapTA, unsigned char* __restrict__ clsA,
                        int* __restrict__ cntA,
                        const int* __restrict__ mapB, int NB,
                        int* __restrict__ mapTB, unsigned char* __restrict__ clsB,
                        int* __restrict__ cntB)
{
    if (blockIdx.y == 0) cls_body(mapA, NA, mapTA, clsA, cntA);
    else                 cls_body(mapB, NB, mapTB, clsB, cntB);
}

// ---------------------------------------------------------------------------
// Pass C body: COMPACT class-grouped scatter (dense order[]).
// ---------------------------------------------------------------------------
__device__ __forceinline__ void scatter_body(const unsigned char* __restrict__ cls,
                                             int Nout,
                                             const int* __restrict__ counts,
                                             int* __restrict__ cursors,
                                             int* __restrict__ order)
{
    __shared__ int hist[9], basec[9];
    const int tid = threadIdx.x;
    const int j   = blockIdx.x * 256 + tid;
    if (tid < 9) hist[tid] = 0;
    const int c9 = (j < Nout) ? (int)cls[j] : -1;
    __syncthreads();
    int lpos = 0;
    if (c9 >= 0) lpos = atomicAdd(&hist[c9], 1);
    __syncthreads();
    if (tid < 9 && hist[tid] > 0)
        basec[tid] = atomicAdd(&cursors[tid], hist[tid]);
    __syncthreads();
    if (c9 >= 0) {
        int offs = 0;
        #pragma unroll
        for (int c = 0; c < 9; ++c)
            if (c < c9) offs += counts[c];
        order[offs + basec[c9] + lpos] = j;
    }
}

__global__ __launch_bounds__(256)
void scatter_compact2(const unsigned char* __restrict__ clsA, int NA,
                      const int* __restrict__ cntA, int* __restrict__ curA,
                      int* __restrict__ orderA,
                      const unsigned char* __restrict__ clsB, int NB,
                      const int* __restrict__ cntB, int* __restrict__ curB,
                      int* __restrict__ orderB)
{
    if (blockIdx.y == 0) scatter_body(clsA, NA, cntA, curA, orderA);
    else                 scatter_body(clsB, NB, cntB, curB, orderB);
}

// ---------------------------------------------------------------------------
// conv0 MFMA (CIN=16 fp32 in, COUT=32, k-PAIRED, compensated hi/lo).
// ---------------------------------------------------------------------------
__global__ __launch_bounds__(256)
void sconv_mf0(const float* __restrict__ x, const _Float16* __restrict__ Wm0,
               const int* __restrict__ map, int Nout,
               _Float16* __restrict__ out, const float* __restrict__ zrow)
{
    const int lane = threadIdx.x & 63;
    const int wave = threadIdx.x >> 6;
    const int row0 = (blockIdx.x * 4 + wave) * 16;

    __shared__ int smap[4][16][28];

    int mk[16];
    bool anyv = false;
    #pragma unroll
    for (int r = 0; r < 16; ++r) {
        const int j = row0 + r;
        mk[r] = (lane < 27 && j < Nout) ? map[(size_t)lane * Nout + j] : -1;
        anyv |= (mk[r] >= 0);
    }
    unsigned long long act = __ballot(anyv);

    if (lane < 27) {
        #pragma unroll
        for (int r = 0; r < 16; ++r)
            smap[wave][r][lane] = mk[r];
    }

    f32x4 accH[2], accL[2];
    #pragma unroll
    for (int c = 0; c < 2; ++c) {
        accH[c] = (f32x4){0.f, 0.f, 0.f, 0.f};
        accL[c] = (f32x4){0.f, 0.f, 0.f, 0.f};
    }

    const int rrow = lane & 15;   // A row / D col
    const int kseg = lane >> 4;
    const int half = kseg & 1;    // cin half: 0 -> 0..7, 1 -> 8..15
    const bool useK1 = (kseg < 2);

    while (act) {
        const int k1 = (int)__builtin_ctzll(act);
        act &= act - 1;
        int k2 = -1;
        if (act) {
            k2 = (int)__builtin_ctzll(act);
            act &= act - 1;
        }
        const int ks = useK1 ? k1 : k2;
        int m = -1;
        if (ks >= 0) m = smap[wave][rrow][ks];

        const float* px = (m >= 0) ? (x + (size_t)m * 16 + half * 8)
                                   : (zrow + half * 8);
        const f4 x0 = *(const f4*)px;
        const f4 x1 = *(const f4*)(px + 4);
        h8 aH, aL;
        #pragma unroll
        for (int u = 0; u < 4; ++u) {
            const float v0 = x0[u], v1 = x1[u];
            const _Float16 h0 = (_Float16)v0;
            const _Float16 h1 = (_Float16)v1;
            aH[u]     = h0;
            aH[u + 4] = h1;
            aL[u]     = (_Float16)((v0 - (float)h0) * 2048.f);
            aL[u + 4] = (_Float16)((v1 - (float)h1) * 2048.f);
        }

        const int ksafe = (ks >= 0) ? ks : 0;   // a==0 makes b irrelevant
        const _Float16* wb = Wm0 + ((size_t)(ksafe * 2 + half) * 32) * 8;
        #pragma unroll
        for (int c = 0; c < 2; ++c) {
            const h8 b = *(const h8*)(wb + (size_t)(c * 16 + rrow) * 8);
            accH[c] = __builtin_amdgcn_mfma_f32_16x16x32_f16(aH, b, accH[c], 0, 0, 0);
            accL[c] = __builtin_amdgcn_mfma_f32_16x16x32_f16(aL, b, accL[c], 0, 0, 0);
        }
    }

    #pragma unroll
    for (int c = 0; c < 2; ++c) {
        #pragma unroll
        for (int r = 0; r < 4; ++r) {
            const int j = row0 + kseg * 4 + r;
            if (j < Nout)
                out[(size_t)j * 32 + c * 16 + rrow] =
                    (_Float16)(accH[c][r] + accL[c][r] * (1.f / 2048.f));
        }
    }
}

// ---------------------------------------------------------------------------
// MFMA sparse conv (UNGROUPED, raw map): NTILE 16-row tiles per wave sharing
// one k-union and B fragments. block2 uses NTILE=1 for latency hiding.
// ---------------------------------------------------------------------------
template<int CIN, int CINA, int COUT, int NTILE>
__global__ __launch_bounds__(256)
void sconv_mf(const _Float16* __restrict__ xA, const _Float16* __restrict__ xB,
              const _Float16* __restrict__ Wm, const int* __restrict__ map,
              int Nout, _Float16* __restrict__ out,
              const _Float16* __restrict__ zrh)
{
    constexpr int CINB = CIN - CINA;
    constexpr int NT = CIN / 32;
    constexpr int NC = COUT / 16;
    constexpr int RPW = NTILE * 16;
    static_assert(CINA % 32 == 0, "CINA must be a multiple of 32");
    const int lane = threadIdx.x & 63;
    const int wave = threadIdx.x >> 6;
    const int row0 = (blockIdx.x * 4 + wave) * RPW;

    __shared__ int smap[4][RPW][28];

    int mv[RPW];
    #pragma unroll
    for (int r = 0; r < RPW; ++r) {
        const int j = row0 + r;
        mv[r] = (lane < 27 && j < Nout) ? map[(size_t)lane * Nout + j] : -1;
    }
    bool anyv = false;
    #pragma unroll
    for (int r = 0; r < RPW; ++r) {
        if (lane < 27) smap[wave][r][lane] = mv[r];
        anyv |= (mv[r] >= 0);
    }
    unsigned long long act = __ballot(anyv) & 0x7FFFFFFull;

    f32x4 acc[NTILE][NC];
    #pragma unroll
    for (int tt = 0; tt < NTILE; ++tt)
        #pragma unroll
        for (int c = 0; c < NC; ++c) acc[tt][c] = (f32x4){0.f, 0.f, 0.f, 0.f};

    const int rrow = lane & 15;
    const int kseg = lane >> 4;

    auto loada = [&](int k, h8 a[NTILE][NT]) {
        #pragma unroll
        for (int tt = 0; tt < NTILE; ++tt) {
            const int m = smap[wave][tt * 16 + rrow][k];
            #pragma unroll
            for (int t = 0; t < NT; ++t) {
                const int cin0 = t * 32 + kseg * 8;
                const _Float16* pa;
                if (m >= 0) {
                    if (CINB > 0 && t * 32 >= CINA)
                        pa = xB + (size_t)m * CINB + (cin0 - CINA);
                    else
                        pa = xA + (size_t)m * CINA + cin0;
                } else {
                    pa = zrh;
                }
                a[tt][t] = *(const h8*)pa;
            }
        }
    };
    auto compute = [&](int k, h8 a[NTILE][NT]) {
        const _Float16* Wk = Wm + ((size_t)k * NT * NC * 64 + lane) * 8;
        #pragma unroll
        for (int t = 0; t < NT; ++t) {
            #pragma unroll
            for (int c = 0; c < NC; ++c) {
                const h8 b = *(const h8*)(Wk + (size_t)(t * NC + c) * 64 * 8);
                #pragma unroll
                for (int tt = 0; tt < NTILE; ++tt)
                    acc[tt][c] = __builtin_amdgcn_mfma_f32_16x16x32_f16(a[tt][t], b, acc[tt][c], 0, 0, 0);
            }
        }
    };

    h8 aC[NTILE][NT], aN[NTILE][NT];
    int kC = -1;
    if (act) {
        kC = (int)__builtin_ctzll(act);
        act &= act - 1;
        loada(kC, aC);
    }
    while (kC >= 0) {
        int kN = -1;
        if (act) {
            kN = (int)__builtin_ctzll(act);
            act &= act - 1;
            loada(kN, aN);
        }
        compute(kC, aC);
        #pragma unroll
        for (int tt = 0; tt < NTILE; ++tt)
            #pragma unroll
            for (int t = 0; t < NT; ++t) aC[tt][t] = aN[tt][t];
        kC = kN;
    }

    #pragma unroll
    for (int tt = 0; tt < NTILE; ++tt) {
        #pragma unroll
        for (int c = 0; c < NC; ++c) {
            #pragma unroll
            for (int r = 0; r < 4; ++r) {
                const int j = row0 + tt * 16 + kseg * 4 + r;
                if (j < Nout)
                    out[(size_t)j * COUT + c * 16 + rrow] = (_Float16)acc[tt][c][r];
            }
        }
    }
}

// ---------------------------------------------------------------------------
// MFMA sparse conv (GROUPED, COMPACT order): 32 order slots/wave, two
// 16-row tiles.
// ---------------------------------------------------------------------------
template<int CIN, int CINA, int COUT>
__global__ __launch_bounds__(256)
void sconv_mf_g(const _Float16* __restrict__ xA, const _Float16* __restrict__ xB,
                const _Float16* __restrict__ Wm, const int* __restrict__ mapT,
                const int* __restrict__ order, int Nout,
                _Float16* __restrict__ out, const _Float16* __restrict__ zrh)
{
    constexpr int CINB = CIN - CINA;
    constexpr int NT = CIN / 32;
    constexpr int NC = COUT / 16;
    static_assert(CINA % 32 == 0, "CINA must be a multiple of 32");
    const int lane = threadIdx.x & 63;
    const int wave = threadIdx.x >> 6;
    const int wrow0 = (blockIdx.x * 4 + wave) * 32;

    __shared__ int sjr[4][32];
    __shared__ int smap[4][32][28];

    int jreg = -1;
    if (lane < 32) {
        const int idx = wrow0 + lane;
        if (idx < Nout) jreg = order[idx];
    }
    if (!__ballot(jreg >= 0)) return;     // tail only (order is compact)
    if (lane < 32) sjr[wave][lane] = jreg;   // epilogue indexing only

    int mv[32];
    #pragma unroll
    for (int r = 0; r < 32; ++r) {
        const int jr = __shfl(jreg, r);
        mv[r] = (jr >= 0 && lane < 27) ? mapT[(size_t)jr * 32 + lane] : -1;
    }
    bool anyv = false;
    #pragma unroll
    for (int r = 0; r < 32; ++r) {
        if (lane < 27) smap[wave][r][lane] = mv[r];
        anyv |= (mv[r] >= 0);
    }
    unsigned long long act = __ballot(anyv) & 0x7FFFFFFull;

    f32x4 acc[2][NC];
    #pragma unroll
    for (int tt = 0; tt < 2; ++tt)
        #pragma unroll
        for (int c = 0; c < NC; ++c) acc[tt][c] = (f32x4){0.f, 0.f, 0.f, 0.f};

    const int rrow = lane & 15;
    const int kseg = lane >> 4;

    auto loada = [&](int k, h8 a[2][NT]) {
        #pragma unroll
        for (int tt = 0; tt < 2; ++tt) {
            const int m = smap[wave][tt * 16 + rrow][k];
            #pragma unroll
            for (int t = 0; t < NT; ++t) {
                const int cin0 = t * 32 + kseg * 8;
                const _Float16* pa;
                if (m >= 0) {
                    if (CINB > 0 && t * 32 >= CINA)
                        pa = xB + (size_t)m * CINB + (cin0 - CINA);
                    else
                        pa = xA + (size_t)m * CINA + cin0;
                } else {
                    pa = zrh;
                }
                a[tt][t] = *(const h8*)pa;
            }
        }
    };
    auto compute = [&](int k, h8 a[2][NT]) {
        const _Float16* Wk = Wm + ((size_t)k * NT * NC * 64 + lane) * 8;
        #pragma unroll
        for (int t = 0; t < NT; ++t) {
            #pragma unroll
            for (int c = 0; c < NC; ++c) {
                const h8 b = *(const h8*)(Wk + (size_t)(t * NC + c) * 64 * 8);
                acc[0][c] = __builtin_amdgcn_mfma_f32_16x16x32_f16(a[0][t], b, acc[0][c], 0, 0, 0);
                acc[1][c] = __builtin_amdgcn_mfma_f32_16x16x32_f16(a[1][t], b, acc[1][c], 0, 0, 0);
            }
        }
    };

    h8 aC[2][NT], aN[2][NT];
    int kC = -1;
    if (act) {
        kC = (int)__builtin_ctzll(act);
        act &= act - 1;
        loada(kC, aC);
    }
    while (kC >= 0) {
        int kN = -1;
        if (act) {
            kN = (int)__builtin_ctzll(act);
            act &= act - 1;
            loada(kN, aN);
        }
        compute(kC, aC);
        #pragma unroll
        for (int tt = 0; tt < 2; ++tt)
            #pragma unroll
            for (int t = 0; t < NT; ++t) aC[tt][t] = aN[tt][t];
        kC = kN;
    }

    #pragma unroll
    for (int tt = 0; tt < 2; ++tt) {
        #pragma unroll
        for (int c = 0; c < NC; ++c) {
            #pragma unroll
            for (int r = 0; r < 4; ++r) {
                const int j = sjr[wave][tt * 16 + kseg * 4 + r];
                if (j >= 0)
                    out[(size_t)j * COUT + c * 16 + rrow] = (_Float16)acc[tt][c][r];
            }
        }
    }
}

// ---------------------------------------------------------------------------
// conv0t GATHER: 2-k pipeline + vectorized loads + XCD swizzle (kept).
// ---------------------------------------------------------------------------
__global__ __launch_bounds__(256)
void sconv0t(const _Float16* __restrict__ d1, const _Float16* __restrict__ s1,
             const float* __restrict__ W /*[27,96,2]*/,
             const int* __restrict__ map, int N, float* __restrict__ out,
             const _Float16* __restrict__ zrh)
{
    const int tid  = threadIdx.x;
    const int lane = tid & 63;
    const int l32  = tid & 31;
    const int bid  = xcd_swz(blockIdx.x, gridDim.x);
    const int j    = bid * 8 + (tid >> 5);

    int mk = (l32 < 27 && j < N) ? map[(size_t)l32 * N + j] : -1;
    const unsigned long long bal = __ballot(mk >= 0);
    unsigned int act = (unsigned int)((bal | (bal >> 32)) & 0x7FFFFFFu);

    float a0 = 0.f, a1 = 0.f;
    while (act) {
        const int k1 = (int)__builtin_ctz(act);
        act &= act - 1;
        int k2 = -1;
        if (act) { k2 = (int)__builtin_ctz(act); act &= act - 1; }
        const int k2s = (k2 >= 0) ? k2 : k1;

        const int m1 = __shfl(mk, (lane & 32) + k1);
        int m2 = __shfl(mk, (lane & 32) + k2s);
        if (k2 < 0) m2 = -1;

        // issue ALL gathers before any FMA
        const _Float16* p1a = (m1 >= 0) ? (d1 + (size_t)m1 * 64) : zrh;
        const _Float16* p1b = (m1 >= 0) ? (s1 + (size_t)m1 * 32) : zrh;
        const _Float16* p2a = (m2 >= 0) ? (d1 + (size_t)m2 * 64) : zrh;
        const _Float16* p2b = (m2 >= 0) ? (s1 + (size_t)m2 * 32) : zrh;
        const h2 xa1 = *(const h2*)(p1a + 2 * l32);
        const float xs1 = (float)p1b[l32];
        const h2 xa2 = *(const h2*)(p2a + 2 * l32);
        const float xs2 = (float)p2b[l32];

        const f4 wa1 = *(const f4*)(W + (size_t)k1 * 192 + 4 * l32);
        const f2 ws1 = *(const f2*)(W + (size_t)k1 * 192 + 128 + 2 * l32);
        const f4 wa2 = *(const f4*)(W + (size_t)k2s * 192 + 4 * l32);
        const f2 ws2 = *(const f2*)(W + (size_t)k2s * 192 + 128 + 2 * l32);

        a0 = fmaf((float)xa1[0], wa1[0], a0);
        a1 = fmaf((float)xa1[0], wa1[1], a1);
        a0 = fmaf((float)xa1[1], wa1[2], a0);
        a1 = fmaf((float)xa1[1], wa1[3], a1);
        a0 = fmaf(xs1, ws1[0], a0);
        a1 = fmaf(xs1, ws1[1], a1);

        a0 = fmaf((float)xa2[0], wa2[0], a0);
        a1 = fmaf((float)xa2[0], wa2[1], a1);
        a0 = fmaf((float)xa2[1], wa2[2], a0);
        a1 = fmaf((float)xa2[1], wa2[3], a1);
        a0 = fmaf(xs2, ws2[0], a0);
        a1 = fmaf(xs2, ws2[1], a1);
    }
    #pragma unroll
    for (int off = 1; off < 32; off <<= 1) {
        a0 += __shfl_xor(a0, off, 32);
        a1 += __shfl_xor(a1, off, 32);
    }
    if (l32 == 0 && j < N) {
        out[(size_t)j * 2 + 0] = a0;
        out[(size_t)j * 2 + 1] = a1;
    }
}

// ---------------------------------------------------------------------------
// BN pass 1, VECTORIZED.
// ---------------------------------------------------------------------------
template<int C>
__global__ __launch_bounds__(256)
void bn_reduce_v(const _Float16* __restrict__ x, int N,
                 float* __restrict__ sums)
{
    constexpr int CV = C / 8;   // h8 vectors per row (4, 8, or 16)
    const int tid  = threadIdx.x;
    const int lane = tid & 63;
    const int wave = tid >> 6;
    const size_t total  = (size_t)N * CV;
    const size_t stride = (size_t)gridDim.x * 256;   // multiple of CV
    const size_t gid    = (size_t)blockIdx.x * 256 + tid;

    float s[8], s2[8];
    #pragma unroll
    for (int u = 0; u < 8; ++u) { s[u] = 0.f; s2[u] = 0.f; }

    for (size_t v = gid; v < total; v += stride) {
        const h8 hv = *(const h8*)(x + v * 8);
        #pragma unroll
        for (int u = 0; u < 8; ++u) {
            const float f = (float)hv[u];
            s[u] += f;
            s2[u] += f * f;
        }
    }

    #pragma unroll
    for (int off = CV; off < 64; off <<= 1) {
        #pragma unroll
        for (int u = 0; u < 8; ++u) {
            s[u]  += __shfl_xor(s[u], off);
            s2[u] += __shfl_xor(s2[u], off);
        }
    }

    __shared__ float shs[4][16][8];
    __shared__ float shq[4][16][8];
    if (lane < CV) {
        #pragma unroll
        for (int u = 0; u < 8; ++u) {
            shs[wave][lane][u] = s[u];
            shq[wave][lane][u] = s2[u];
        }
    }
    __syncthreads();
    if (tid < C) {
        const int ph = tid >> 3, u = tid & 7;
        float ts = 0.f, tq = 0.f;
        #pragma unroll
        for (int w = 0; w < 4; ++w) {
            ts += shs[w][ph][u];
            tq += shq[w][ph][u];
        }
        atomicAdd(&sums[tid], ts);
        atomicAdd(&sums[C + tid], tq);
    }
}

// ---------------------------------------------------------------------------
// BN pass 2, VECTORIZED.
// ---------------------------------------------------------------------------
template<int C>
__global__ __launch_bounds__(256)
void bn_apply_v(_Float16* __restrict__ x, int N,
                const float* __restrict__ sums,
                const float* __restrict__ g, const float* __restrict__ b)
{
    constexpr int CV = C / 8;
    const size_t total  = (size_t)N * CV;
    const size_t stride = (size_t)gridDim.x * 256;   // multiple of CV
    const size_t gid    = (size_t)blockIdx.x * 256 + threadIdx.x;
    const int phase = (int)(gid % CV);

    const float invN = 1.0f / (float)N;
    float sc[8], sh[8];
    #pragma unroll
    for (int u = 0; u < 8; ++u) {
        const int c = phase * 8 + u;
        const float mean = sums[c] * invN;
        float var = sums[C + c] * invN - mean * mean;
        var = fmaxf(var, 0.f);
        sc[u] = g[c] * rsqrtf(var + BN_EPS);
        sh[u] = b[c] - mean * sc[u];
    }

    for (size_t v = gid; v < total; v += stride) {
        h8 hv = *(h8*)(x + v * 8);
        #pragma unroll
        for (int u = 0; u < 8; ++u) {
            const float f = fmaf((float)hv[u], sc[u], sh[u]);
            hv[u] = (_Float16)(f > 0.f ? f : 0.f);
        }
        *(h8*)(x + v * 8) = hv;
    }
}

// ---------------------------------------------------------------------------
extern "C" void kernel_launch(void* const* d_in, const int* in_sizes, int n_in,
                              void* d_out, int out_size, void* d_ws, size_t ws_size,
                              hipStream_t stream)
{
    const float* feats = (const float*)d_in[0];
    const float* W0  = (const float*)d_in[1];
    const float* g0  = (const float*)d_in[2];
    const float* b0  = (const float*)d_in[3];
    const float* W1  = (const float*)d_in[4];
    const float* g1  = (const float*)d_in[5];
    const float* b1  = (const float*)d_in[6];
    const float* W2  = (const float*)d_in[7];
    const float* g2  = (const float*)d_in[8];
    const float* b2  = (const float*)d_in[9];
    const float* W2t = (const float*)d_in[10];
    const float* g2t = (const float*)d_in[11];
    const float* b2t = (const float*)d_in[12];
    const float* W1t = (const float*)d_in[13];
    const float* g1t = (const float*)d_in[14];
    const float* b1t = (const float*)d_in[15];
    const float* W0t = (const float*)d_in[16];
    const int* map0  = (const int*)d_in[17];
    const int* map1  = (const int*)d_in[18];
    const int* map2  = (const int*)d_in[19];
    const int* map2t = (const int*)d_in[20];
    const int* map1t = (const int*)d_in[21];
    const int* map0t = (const int*)d_in[22];

    const int N0 = in_sizes[0] / 16;
    const int N1 = in_sizes[18] / 27;
    const int N2 = in_sizes[19] / 27;

    float* ws = (float*)d_ws;
    float* sums  = ws;          // 704 floats of BN accumulators
    float* sums0 = sums;        // 2*32
    float* sums1 = sums + 64;   // 2*64
    float* sums2 = sums + 192;  // 2*128
    float* sums3 = sums + 448;  // 2*64
    float* sums4 = sums + 576;  // 2*64
    float* zrow  = sums + 704;  // 128 zeroed floats (fp32 & f16 zero rows)
    int*   gcnt  = (int*)(zrow + 128);  // 64 ints: {cnt2t[9],cur2t[9]} @0/16, {cnt1t[9],cur1t[9]} @32/48
    _Float16* Wm0h = (_Float16*)(gcnt + 64);    // 27*2*32*8 f16 (paired MFMA)
    _Float16* Wh1  = Wm0h + 27 * 2 * 32 * 8;    // 27*32*64  (MFMA layout)
    _Float16* Wh2  = Wh1 + 27 * 32 * 64;        // 27*64*128  (MFMA layout)
    _Float16* Wh2t = Wh2 + 27 * 64 * 128;       // 27*128*64  (MFMA layout)
    _Float16* Wh1t = Wh2t + 27 * 128 * 64;      // 27*128*64  (MFMA layout)
    _Float16* y0 = Wh1t + 27 * 128 * 64;        // [N0,32]  s1
    _Float16* y1 = y0 + (size_t)N0 * 32;        // [N1,64]  s2
    _Float16* y2 = y1 + (size_t)N1 * 64;        // [N2,128] s4
    _Float16* y3 = y2 + (size_t)N2 * 128;       // [N1,64]  d2
    _Float16* y4 = y3 + (size_t)N1 * 64;        // [N0,64]  d1
    int* mapT1 = (int*)(y4 + (size_t)N0 * 64);  // [N1,32] block2_tr transposed map
    int* mapT0 = mapT1 + (size_t)N1 * 32;       // [N0,32] block1_tr transposed map
    int* orderA = mapT0 + (size_t)N0 * 32;      // [N1] compact block2_tr order
    int* orderB = orderA + N1;                  // [N0] compact block1_tr order
    unsigned char* clsA = (unsigned char*)(orderB + N0);  // [N1] class bytes
    unsigned char* clsB = clsA + N1;                      // [N0] class bytes
    const _Float16* zrh = (const _Float16*)zrow;

    (void)hipMemsetAsync(sums, 0, (704 + 128 + 64) * sizeof(float), stream);

    // all 5 weight transforms in ONE launch (round-20: launch consolidation)
    wtrans_all<<<(91584 + 255) / 256, 256, 0, stream>>>(
        W0, W1, W2, W2t, W1t, Wm0h, Wh1, Wh2, Wh2t, Wh1t);

    // grouping prep for BOTH transpose blocks, 2 launches total (was 4),
    // hoisted before the convs (depends only on input maps)
    {
        const int bx = ((N0 > N1 ? N0 : N1) + 255) / 256;
        map_transpose_cls2<<<dim3(bx, 2), 256, 0, stream>>>(
            map2t, N1, mapT1, clsA, gcnt,
            map1t, N0, mapT0, clsB, gcnt + 32);
        scatter_compact2<<<dim3(bx, 2), 256, 0, stream>>>(
            clsA, N1, gcnt, gcnt + 16, orderA,
            clsB, N0, gcnt + 32, gcnt + 48, orderB);
    }

    // block0: feats[N0,16] fp32 -> y0[N0,32] half. MFMA k-paired hi/lo.
    sconv_mf0<<<(N0 + 63) / 64, 256, 0, stream>>>(
        feats, Wm0h, map0, N0, y0, zrow);
    bn_reduce_v<32><<<512, 256, 0, stream>>>(y0, N0, sums0);
    bn_apply_v<32><<<1024, 256, 0, stream>>>(y0, N0, sums0, g0, b0);

    // block1: MFMA ungrouped, 32 rows/wave
    sconv_mf<32, 32, 64, 2><<<(N1 + 127) / 128, 256, 0, stream>>>(
        y0, nullptr, Wh1, map1, N1, y1, zrh);
    bn_reduce_v<64><<<512, 256, 0, stream>>>(y1, N1, sums1);
    bn_apply_v<64><<<1024, 256, 0, stream>>>(y1, N1, sums1, g1, b1);

    // block2: MFMA, 16 rows/wave (2x waves for latency hiding)
    sconv_mf<64, 64, 128, 1><<<(N2 + 63) / 64, 256, 0, stream>>>(
        y1, nullptr, Wh2, map2, N2, y2, zrh);
    bn_reduce_v<128><<<512, 256, 0, stream>>>(y2, N2, sums2);
    bn_apply_v<128><<<1024, 256, 0, stream>>>(y2, N2, sums2, g2, b2);

    // block2_tr: parity-grouped MFMA on a COMPACT order
    sconv_mf_g<128, 128, 64><<<(N1 + 127) / 128, 256, 0, stream>>>(
        y2, nullptr, Wh2t, mapT1, orderA, N1, y3, zrh);
    bn_reduce_v<64><<<512, 256, 0, stream>>>(y3, N1, sums3);
    bn_apply_v<64><<<1024, 256, 0, stream>>>(y3, N1, sums3, g2t, b2t);

    // block1_tr: parity-grouped MFMA on a COMPACT order, concat (y3 ++ y1)
    sconv_mf_g<128, 64, 64><<<(N0 + 127) / 128, 256, 0, stream>>>(
        y3, y1, Wh1t, mapT0, orderB, N0, y4, zrh);
    bn_reduce_v<64><<<512, 256, 0, stream>>>(y4, N0, sums4);
    bn_apply_v<64><<<1024, 256, 0, stream>>>(y4, N0, sums4, g1t, b1t);

    // block0_tr: gather conv (2-k pipelined, vectorized, XCD-swizzled)
    sconv0t<<<(N0 + 7) / 8, 256, 0, stream>>>(y4, y0, W0t, map0t, N0,
                                              (float*)d_out, zrh);
}